// Round 1
// baseline (1017.319 us; speedup 1.0000x reference)
//
#include <hip/hip_runtime.h>
#include <hip/hip_bf16.h>

#define H64 64

typedef __bf16 bf16_t;
typedef __bf16 bf16x8 __attribute__((ext_vector_type(8)));
typedef float f32x4 __attribute__((ext_vector_type(4)));

// ---------- helpers ----------
__device__ __forceinline__ float wload(const void* p, long i, bool f32) {
    return f32 ? ((const float*)p)[i]
               : __bfloat162float(((const __hip_bfloat16*)p)[i]);
}
__device__ __forceinline__ float blo(unsigned v) { return __uint_as_float(v << 16); }
__device__ __forceinline__ float bhi(unsigned v) { return __uint_as_float(v & 0xffff0000u); }

// ---------- runtime format detection ----------
// flags[0] != 0 -> edge indices int32 (odd words nonzero); ==0 -> int64
// flags[1] > 64 -> x tensors f32; else bf16.  flags[2] > 64 -> weights f32.
__global__ void detect_k(const unsigned int* __restrict__ eiw, int nwords,
                         const unsigned short* __restrict__ xw,
                         const unsigned short* __restrict__ ww,
                         unsigned int* __restrict__ flags) {
    int t = threadIdx.x;
    unsigned int acc = 0;
    for (int i = 1 + 2 * t; i < nwords; i += 512) acc |= eiw[i];
    if (acc) atomicOr(&flags[0], acc);
    unsigned int cx = 0, cw = 0;
    for (int i = t; i < 8192; i += 256) {
        unsigned short w = xw[i];
        unsigned int e = (w >> 7) & 0xFF;
        if ((w & 0x7FFF) && (e == 0xFF || e < 0x40)) cx++;
        w = ww[i];
        e = (w >> 7) & 0xFF;
        if ((w & 0x7FFF) && (e == 0xFF || e < 0x40)) cw++;
    }
    if (cx) atomicAdd(&flags[1], cx);
    if (cw) atomicAdd(&flags[2], cw);
}

// ---------- convert all x inputs -> bf16 ws storage (single dispatch) ----------
struct ConvArgs {
    const void* src[4];
    long elemoff[5];   // element offsets (rows*64) per type, cumulative
};
__global__ void conv_in_all(ConvArgs ca, __hip_bfloat16* __restrict__ dst,
                            const unsigned int* __restrict__ flags) {
    bool xf32 = flags[1] > 64;
    long n = ca.elemoff[4];
    long i = (long)blockIdx.x * blockDim.x + threadIdx.x;
    long stride = (long)gridDim.x * blockDim.x;
    for (; i < n; i += stride) {
        int t = (i >= ca.elemoff[2]) ? (i >= ca.elemoff[3] ? 3 : 2)
                                     : (i >= ca.elemoff[1] ? 1 : 0);
        long j = i - ca.elemoff[t];
        float v = xf32 ? ((const float*)ca.src[t])[j]
                       : __bfloat162float(((const __hip_bfloat16*)ca.src[t])[j]);
        dst[i] = __float2bfloat16(v);
    }
}

// ---------- weight prep: bf16, transposed WT[n][k]; Wr pre-summed per (l,dt) ----------
// blockIdx.x = l*13 + p.  p<9: WT of Wl[l,p].  p in 9..12: dt=p-9, WT of sum(Wr) + blsum.
__global__ void prep_w(const void* __restrict__ Wl, const void* __restrict__ Wr,
                       const void* __restrict__ bl, const unsigned int* __restrict__ flags,
                       bf16_t* __restrict__ wt, float* __restrict__ blsum) {
    const int rel_dt[9] = {0, 1, 2, 1, 2, 2, 3, 3, 3};
    bool wf32 = flags[2] > 64;
    int l = blockIdx.x / 13, p = blockIdx.x % 13;
    bf16_t* dst = wt + (long)blockIdx.x * 4096;
    for (int i = threadIdx.x; i < 4096; i += 256) {
        int n = i >> 6, k = i & 63;
        float v;
        if (p < 9) {
            v = wload(Wl, (long)(l * 9 + p) * 4096 + k * 64 + n, wf32);
        } else {
            int dt = p - 9;
            v = 0.f;
            for (int r = 0; r < 9; ++r)
                if (rel_dt[r] == dt) v += wload(Wr, (long)(l * 9 + r) * 4096 + k * 64 + n, wf32);
        }
        __hip_bfloat16 h = __float2bfloat16(v);
        dst[i] = *(bf16_t*)&h;
    }
    if (p >= 9 && threadIdx.x < 64) {
        int dt = p - 9;
        float s = 0.f;
        for (int r = 0; r < 9; ++r)
            if (rel_dt[r] == dt) s += wload(bl, (long)(l * 9 + r) * 64 + threadIdx.x, wf32);
        blsum[(l * 4 + dt) * 64 + threadIdx.x] = s;
    }
}

// ---------- consolidated CSR build ----------
struct EdgeArgs {
    const int* ei[9];
    long eoff[10];
    int cntoff[9];
    int srcbase[9];
};

// count + emit per-edge rank (coalesced)
__global__ void count_all(EdgeArgs ea, const unsigned int* __restrict__ flags,
                          int* __restrict__ cnt, int* __restrict__ rank) {
    long e = (long)blockIdx.x * 256 + threadIdx.x;
    if (e >= ea.eoff[9]) return;
    int r = 0;
    while (r < 8 && e >= ea.eoff[r + 1]) ++r;
    long el = e - ea.eoff[r];
    long E = ea.eoff[r + 1] - ea.eoff[r];
    bool is64 = (flags[0] == 0u);
    const int* ei = ea.ei[r];
    int dst = is64 ? ei[2 * E + 2 * el] : ei[E + el];
    rank[e] = atomicAdd(&cnt[ea.cntoff[r] + dst], 1);
}

// atomic-free fill: pos = row_ptr[dst] + rank[e]
__global__ void fill_all(EdgeArgs ea, const unsigned int* __restrict__ flags,
                         const int* __restrict__ row_ptr, const int* __restrict__ rank,
                         int* __restrict__ edge_src) {
    long e = (long)blockIdx.x * 256 + threadIdx.x;
    if (e >= ea.eoff[9]) return;
    int r = 0;
    while (r < 8 && e >= ea.eoff[r + 1]) ++r;
    long el = e - ea.eoff[r];
    long E = ea.eoff[r + 1] - ea.eoff[r];
    bool is64 = (flags[0] == 0u);
    const int* ei = ea.ei[r];
    int src, dst;
    if (is64) { src = ei[2 * el]; dst = ei[2 * E + 2 * el]; }
    else      { src = ei[el];     dst = ei[E + el]; }
    int pos = row_ptr[ea.cntoff[r] + dst] + rank[e];
    edge_src[pos] = ea.srcbase[r] + src;
}

__global__ void scan_bsum(const int* __restrict__ cnt, int n, int* __restrict__ bsums) {
    __shared__ int red[256];
    int i = blockIdx.x * 256 + threadIdx.x;
    red[threadIdx.x] = (i < n) ? cnt[i] : 0;
    __syncthreads();
    for (int s = 128; s; s >>= 1) {
        if (threadIdx.x < s) red[threadIdx.x] += red[threadIdx.x + s];
        __syncthreads();
    }
    if (threadIdx.x == 0) bsums[blockIdx.x] = red[0];
}

__global__ void scan_excl_single(int* __restrict__ data, int n) {
    __shared__ int buf[1024];
    __shared__ int carry_s;
    if (threadIdx.x == 0) carry_s = 0;
    __syncthreads();
    for (int base = 0; base < n; base += 1024) {
        int i = base + threadIdx.x;
        int v = (i < n) ? data[i] : 0;
        buf[threadIdx.x] = v;
        __syncthreads();
        for (int off = 1; off < 1024; off <<= 1) {
            int tv = (threadIdx.x >= off) ? buf[threadIdx.x - off] : 0;
            __syncthreads();
            buf[threadIdx.x] += tv;
            __syncthreads();
        }
        int incl = buf[threadIdx.x];
        int carry = carry_s;
        if (i < n) data[i] = carry + incl - v;
        __syncthreads();
        if (threadIdx.x == 1023) carry_s = carry + buf[1023];
        __syncthreads();
    }
}

__global__ void scan_rowptr(const int* __restrict__ cnt, const int* __restrict__ bsums,
                            int n, int* __restrict__ row_ptr) {
    __shared__ int buf[256];
    int i = blockIdx.x * 256 + threadIdx.x;
    int v = (i < n) ? cnt[i] : 0;
    buf[threadIdx.x] = v;
    __syncthreads();
    for (int off = 1; off < 256; off <<= 1) {
        int tv = (threadIdx.x >= off) ? buf[threadIdx.x - off] : 0;
        __syncthreads();
        buf[threadIdx.x] += tv;
        __syncthreads();
    }
    int excl = buf[threadIdx.x] - v + bsums[blockIdx.x];
    if (i < n) row_ptr[i] = excl;
    if (i == n - 1) row_ptr[n] = excl + v;
}

// ---------- gather-mean: half-wave (32 lanes) per dst row, unroll 16 ----------
__global__ void gather_mean(const __hip_bfloat16* __restrict__ x,
                            const int* __restrict__ edge_src,
                            const int* __restrict__ row_ptr,
                            __hip_bfloat16* __restrict__ agg, int nrows) {
    int w = blockIdx.x * 8 + (threadIdx.x >> 5);
    int lane = threadIdx.x & 31;
    if (w >= nrows) return;
    int s = row_ptr[w], t = row_ptr[w + 1];
    const unsigned* xu = (const unsigned*)x;
    float a0 = 0.f, a1 = 0.f;
    int e = s;
    for (; e + 16 <= t; e += 16) {
        unsigned v[16];
        #pragma unroll
        for (int u = 0; u < 16; ++u) v[u] = xu[(long)edge_src[e + u] * 32 + lane];
        #pragma unroll
        for (int u = 0; u < 16; ++u) { a0 += blo(v[u]); a1 += bhi(v[u]); }
    }
    for (; e + 4 <= t; e += 4) {
        unsigned v0 = xu[(long)edge_src[e] * 32 + lane];
        unsigned v1 = xu[(long)edge_src[e + 1] * 32 + lane];
        unsigned v2 = xu[(long)edge_src[e + 2] * 32 + lane];
        unsigned v3 = xu[(long)edge_src[e + 3] * 32 + lane];
        a0 += (blo(v0) + blo(v1)) + (blo(v2) + blo(v3));
        a1 += (bhi(v0) + bhi(v1)) + (bhi(v2) + bhi(v3));
    }
    for (; e < t; ++e) {
        unsigned v = xu[(long)edge_src[e] * 32 + lane];
        a0 += blo(v); a1 += bhi(v);
    }
    float inv = (t > s) ? 1.0f / (float)(t - s) : 0.f;
    __hip_bfloat162 o;
    o.x = __float2bfloat16(a0 * inv);
    o.y = __float2bfloat16(a1 * inv);
    ((__hip_bfloat162*)agg)[(long)w * 32 + lane] = o;
}

// ---------- layer update: register-resident weights, direct-global A, no LDS ----------
// x[d,:] = relu( sum_p agg_p[d,:] @ Wl_p + x[d,:] @ Wsum + blsum ),  in place.
struct UpdArgs {
    long aggOff[4][3];
    int wtSlot[4][4];
    long dstBase[4];
    int nDst[4];
    int Rdt[4];
    int blsumOff[4];
    int btBase[5];
    int totalBT;
};

__global__ __launch_bounds__(256) void update_layer(
    __hip_bfloat16* __restrict__ x,
    const __hip_bfloat16* __restrict__ agg,
    const bf16_t* __restrict__ wt,
    const float* __restrict__ blsum,
    UpdArgs ua, int btPerBlk) {
    int wv = threadIdx.x >> 6;
    int lane = threadIdx.x & 63;
    int quad = lane >> 4, l16 = lane & 15;
    int bt0 = blockIdx.x * btPerBlk;
    int bt1 = bt0 + btPerBlk;
    if (bt1 > ua.totalBT) bt1 = ua.totalBT;
    int curdt = -1;
    bf16x8 B[4][4][2];   // [pass][nt][kc] — compile-time indexed only

    for (int bt = bt0; bt < bt1; ++bt) {
        int slot = 0;
        while (slot < 3 && bt >= ua.btBase[slot + 1]) ++slot;
        int dt = slot;
        int R = ua.Rdt[dt];
        if (dt != curdt) {
            curdt = dt;
            #pragma unroll
            for (int p = 0; p < 4; ++p) {
                if (p <= R) {
                    const bf16_t* wb = wt + (long)ua.wtSlot[dt][p == R ? 3 : p] * 4096;
                    #pragma unroll
                    for (int nt = 0; nt < 4; ++nt)
                        #pragma unroll
                        for (int kc = 0; kc < 2; ++kc)
                            B[p][nt][kc] = *(const bf16x8*)(wb + (nt * 16 + l16) * 64 + kc * 32 + quad * 8);
                }
            }
        }
        long d0 = (long)(bt - ua.btBase[slot]) * 64 + wv * 16;
        f32x4 acc[4] = {};
        #pragma unroll
        for (int p = 0; p < 4; ++p) {
            if (p <= R) {
                const bf16_t* abase = (p == R)
                    ? (const bf16_t*)x + (ua.dstBase[dt] + d0) * 64
                    : (const bf16_t*)agg + (ua.aggOff[dt][p == R ? 0 : p] + d0) * 64;
                bf16x8 a0 = *(const bf16x8*)(abase + l16 * 64 + quad * 8);
                bf16x8 a1 = *(const bf16x8*)(abase + l16 * 64 + 32 + quad * 8);
                #pragma unroll
                for (int nt = 0; nt < 4; ++nt) {
                    acc[nt] = __builtin_amdgcn_mfma_f32_16x16x32_bf16(a0, B[p][nt][0], acc[nt], 0, 0, 0);
                    acc[nt] = __builtin_amdgcn_mfma_f32_16x16x32_bf16(a1, B[p][nt][1], acc[nt], 0, 0, 0);
                }
            }
        }
        const float* bs = blsum + ua.blsumOff[dt];
        int n_dst = ua.nDst[dt];
        #pragma unroll
        for (int nt = 0; nt < 4; ++nt) {
            int col = nt * 16 + l16;
            float bv = bs[col];
            #pragma unroll
            for (int reg = 0; reg < 4; ++reg) {
                long dd = d0 + quad * 4 + reg;
                if (dd < n_dst)
                    x[(ua.dstBase[dt] + dd) * 64 + col] =
                        __float2bfloat16(fmaxf(acc[nt][reg] + bv, 0.f));
            }
        }
    }
}

// ---------- head: softplus(x@projW+projb) @ outW + outb ----------
__global__ __launch_bounds__(256) void head_k(
    const __hip_bfloat16* __restrict__ xc,
    const void* __restrict__ projW, const void* __restrict__ projb,
    const void* __restrict__ outW, const void* __restrict__ outb,
    void* __restrict__ out, const unsigned int* __restrict__ flags, int n) {
    __shared__ float PW[64 * 64];
    __shared__ float PB[64], OW[64];
    __shared__ float ROW[4][64];
    bool wf32 = flags[2] > 64;
    bool of32 = flags[1] > 64;
    int t = threadIdx.x;
    for (int i = t; i < 4096; i += 256) PW[i] = wload(projW, i, wf32);
    if (t < 64) { PB[t] = wload(projb, t, wf32); OW[t] = wload(outW, t, wf32); }
    int wid = t >> 6, lane = t & 63;
    int d = blockIdx.x * 4 + wid;
    ROW[wid][lane] = (d < n) ? __bfloat162float(xc[(long)d * H64 + lane]) : 0.f;
    __syncthreads();
    if (d < n) {
        float s = PB[lane];
        #pragma unroll 8
        for (int k = 0; k < 64; ++k) s += ROW[wid][k] * PW[k * 64 + lane];
        float sp = fmaxf(s, 0.f) + log1pf(expf(-fabsf(s)));
        float c = sp * OW[lane];
        #pragma unroll
        for (int off = 32; off; off >>= 1) c += __shfl_down(c, off, 64);
        if (lane == 0) {
            float rv = c + wload(outb, 0, wf32);
            if (of32) ((float*)out)[d] = rv;
            else ((__hip_bfloat16*)out)[d] = __float2bfloat16(rv);
        }
    }
}

extern "C" void kernel_launch(void* const* d_in, const int* in_sizes, int n_in,
                              void* d_out, int out_size, void* d_ws, size_t ws_size,
                              hipStream_t stream) {
    static const int rel_st[9] = {0, 0, 0, 1, 1, 2, 0, 1, 2};
    static const int rel_dt[9] = {0, 1, 2, 1, 2, 2, 3, 3, 3};
    static const int relsOf[4][3] = {{0, -1, -1}, {1, 3, -1}, {2, 4, 5}, {6, 7, 8}};
    static const int Rof[4] = {1, 2, 3, 3};

    long rows[4], rowoff[4], total = 0;
    for (int t = 0; t < 4; ++t) { rows[t] = in_sizes[t] / H64; rowoff[t] = total; total += rows[t]; }
    long NX = total * H64;
    long Es[9], ET = 0;
    for (int r = 0; r < 9; ++r) { Es[r] = (long)in_sizes[11 + r] / 2; ET += Es[r]; }
    long cntoff[9], cntN = 0;
    for (int r = 0; r < 9; ++r) { cntoff[r] = cntN; cntN += rows[rel_dt[r]]; }
    long nb1 = (cntN + 255) / 256;

    unsigned int* flags = (unsigned int*)d_ws;
    char* wsbase = (char*)d_ws + 64;
    auto align16 = [](size_t v) { return (v + 15) & ~(size_t)15; };
    size_t off = 0;
    __hip_bfloat16* x = (__hip_bfloat16*)(wsbase + off);   off = align16(off + (size_t)NX * 2);
    __hip_bfloat16* agg = (__hip_bfloat16*)(wsbase + off); off = align16(off + (size_t)cntN * H64 * 2);
    int* cnt_i = (int*)(wsbase + off);                     off = align16(off + (size_t)cntN * 4);
    int* row_ptr = (int*)(wsbase + off);                   off = align16(off + (size_t)(cntN + 1) * 4);
    int* rank = (int*)(wsbase + off);                      off = align16(off + (size_t)ET * 4);
    int* edge_src = (int*)(wsbase + off);                  off = align16(off + (size_t)ET * 4);
    int* bsums = (int*)(wsbase + off);                     off = align16(off + (size_t)nb1 * 4);
    bf16_t* wt = (bf16_t*)(wsbase + off);                  off = align16(off + (size_t)39 * 4096 * 2);
    float* blsum = (float*)(wsbase + off);                 off = align16(off + (size_t)12 * 64 * 4);

    // format detection
    hipMemsetAsync(d_ws, 0, 64, stream);
    int nwords = 16384;
    if (in_sizes[11] < nwords) nwords = in_sizes[11];
    detect_k<<<1, 256, 0, stream>>>((const unsigned int*)d_in[11], nwords,
                                    (const unsigned short*)d_in[0],
                                    (const unsigned short*)d_in[4], flags);

    // x inputs -> bf16 ws (single dispatch)
    ConvArgs ca;
    for (int t = 0; t < 4; ++t) { ca.src[t] = d_in[t]; ca.elemoff[t] = rowoff[t] * H64; }
    ca.elemoff[4] = NX;
    {
        int blocks = (int)((NX + 255) / 256); if (blocks > 8192) blocks = 8192;
        conv_in_all<<<blocks, 256, 0, stream>>>(ca, x, flags);
    }

    // weight prep (transpose + pre-sum, bf16)
    prep_w<<<39, 256, 0, stream>>>(d_in[4], d_in[6], d_in[5], flags, wt, blsum);

    // CSR build (edge structure is layer-invariant)
    EdgeArgs ea;
    long ecum = 0;
    for (int r = 0; r < 9; ++r) {
        ea.ei[r] = (const int*)d_in[11 + r];
        ea.eoff[r] = ecum; ecum += Es[r];
        ea.cntoff[r] = (int)cntoff[r];
        ea.srcbase[r] = (int)rowoff[rel_st[r]];
    }
    ea.eoff[9] = ecum;

    hipMemsetAsync(cnt_i, 0, (size_t)cntN * 4, stream);
    count_all<<<(int)((ET + 255) / 256), 256, 0, stream>>>(ea, flags, cnt_i, rank);
    scan_bsum<<<(int)nb1, 256, 0, stream>>>(cnt_i, (int)cntN, bsums);
    scan_excl_single<<<1, 1024, 0, stream>>>(bsums, (int)nb1);
    scan_rowptr<<<(int)nb1, 256, 0, stream>>>(cnt_i, bsums, (int)cntN, row_ptr);
    fill_all<<<(int)((ET + 255) / 256), 256, 0, stream>>>(ea, flags, row_ptr, rank, edge_src);

    // update-layer argument block (layer-invariant parts)
    UpdArgs ua;
    int bb = 0;
    for (int dt = 0; dt < 4; ++dt) {
        ua.nDst[dt] = (int)rows[dt];
        ua.Rdt[dt] = Rof[dt];
        ua.dstBase[dt] = rowoff[dt];
        ua.btBase[dt] = bb;
        bb += (int)((rows[dt] + 63) / 64);
        for (int p = 0; p < 3; ++p) {
            int rr = (p < Rof[dt]) ? relsOf[dt][p] : relsOf[dt][0];
            ua.aggOff[dt][p] = cntoff[rr];
        }
    }
    ua.btBase[4] = bb;
    ua.totalBT = bb;
    int btPerBlk = (bb + 1023) / 1024;
    if (btPerBlk < 1) btPerBlk = 1;
    int updGrid = (bb + btPerBlk - 1) / btPerBlk;

    // layers: gather (x -> agg), then in-place MFMA update
    for (int l = 0; l < 3; ++l) {
        gather_mean<<<(int)((cntN + 7) / 8), 256, 0, stream>>>(
            x, edge_src, row_ptr, agg, (int)cntN);
        for (int dt = 0; dt < 4; ++dt) {
            ua.blsumOff[dt] = (l * 4 + dt) * 64;
            for (int p = 0; p < 3; ++p) {
                int rr = (p < Rof[dt]) ? relsOf[dt][p] : relsOf[dt][0];
                ua.wtSlot[dt][p] = l * 13 + rr;
            }
            ua.wtSlot[dt][3] = l * 13 + 9 + dt;
        }
        update_layer<<<updGrid, 256, 0, stream>>>(x, agg, wt, blsum, ua, btPerBlk);
    }

    head_k<<<(int)((rows[3] + 3) / 4), 256, 0, stream>>>(
        x + rowoff[3] * H64, d_in[7], d_in[8], d_in[9], d_in[10], d_out, flags, (int)rows[3]);
}

// Round 2
// 960.603 us; speedup vs baseline: 1.0590x; 1.0590x over previous
//
#include <hip/hip_runtime.h>
#include <hip/hip_bf16.h>

#define H64 64

typedef __bf16 bf16_t;
typedef __bf16 bf16x8 __attribute__((ext_vector_type(8)));
typedef float f32x4 __attribute__((ext_vector_type(4)));

// ---------- helpers ----------
__device__ __forceinline__ float wload(const void* p, long i, bool f32) {
    return f32 ? ((const float*)p)[i]
               : __bfloat162float(((const __hip_bfloat16*)p)[i]);
}
__device__ __forceinline__ float blo(unsigned v) { return __uint_as_float(v << 16); }
__device__ __forceinline__ float bhi(unsigned v) { return __uint_as_float(v & 0xffff0000u); }

// ---------- runtime format detection ----------
// flags[0] != 0 -> edge indices int32 (odd words nonzero); ==0 -> int64
// flags[1] > 64 -> x tensors f32; else bf16.  flags[2] > 64 -> weights f32.
__global__ void detect_k(const unsigned int* __restrict__ eiw, int nwords,
                         const unsigned short* __restrict__ xw,
                         const unsigned short* __restrict__ ww,
                         unsigned int* __restrict__ flags) {
    int t = threadIdx.x;
    unsigned int acc = 0;
    for (int i = 1 + 2 * t; i < nwords; i += 512) acc |= eiw[i];
    if (acc) atomicOr(&flags[0], acc);
    unsigned int cx = 0, cw = 0;
    for (int i = t; i < 8192; i += 256) {
        unsigned short w = xw[i];
        unsigned int e = (w >> 7) & 0xFF;
        if ((w & 0x7FFF) && (e == 0xFF || e < 0x40)) cx++;
        w = ww[i];
        e = (w >> 7) & 0xFF;
        if ((w & 0x7FFF) && (e == 0xFF || e < 0x40)) cw++;
    }
    if (cx) atomicAdd(&flags[1], cx);
    if (cw) atomicAdd(&flags[2], cw);
}

// ---------- convert all x inputs -> bf16 ws storage (single dispatch) ----------
struct ConvArgs {
    const void* src[4];
    long elemoff[5];   // element offsets (rows*64) per type, cumulative
};
__global__ void conv_in_all(ConvArgs ca, __hip_bfloat16* __restrict__ dst,
                            const unsigned int* __restrict__ flags) {
    bool xf32 = flags[1] > 64;
    long n = ca.elemoff[4];
    long i = (long)blockIdx.x * blockDim.x + threadIdx.x;
    long stride = (long)gridDim.x * blockDim.x;
    for (; i < n; i += stride) {
        int t = (i >= ca.elemoff[2]) ? (i >= ca.elemoff[3] ? 3 : 2)
                                     : (i >= ca.elemoff[1] ? 1 : 0);
        long j = i - ca.elemoff[t];
        float v = xf32 ? ((const float*)ca.src[t])[j]
                       : __bfloat162float(((const __hip_bfloat16*)ca.src[t])[j]);
        dst[i] = __float2bfloat16(v);
    }
}

// ---------- weight prep: bf16, transposed WT[n][k]; Wr pre-summed per (l,dt) ----------
// blockIdx.x = l*13 + p.  p<9: WT of Wl[l,p].  p in 9..12: dt=p-9, WT of sum(Wr) + blsum.
__global__ void prep_w(const void* __restrict__ Wl, const void* __restrict__ Wr,
                       const void* __restrict__ bl, const unsigned int* __restrict__ flags,
                       bf16_t* __restrict__ wt, float* __restrict__ blsum) {
    const int rel_dt[9] = {0, 1, 2, 1, 2, 2, 3, 3, 3};
    bool wf32 = flags[2] > 64;
    int l = blockIdx.x / 13, p = blockIdx.x % 13;
    bf16_t* dst = wt + (long)blockIdx.x * 4096;
    for (int i = threadIdx.x; i < 4096; i += 256) {
        int n = i >> 6, k = i & 63;
        float v;
        if (p < 9) {
            v = wload(Wl, (long)(l * 9 + p) * 4096 + k * 64 + n, wf32);
        } else {
            int dt = p - 9;
            v = 0.f;
            for (int r = 0; r < 9; ++r)
                if (rel_dt[r] == dt) v += wload(Wr, (long)(l * 9 + r) * 4096 + k * 64 + n, wf32);
        }
        __hip_bfloat16 h = __float2bfloat16(v);
        dst[i] = *(bf16_t*)&h;
    }
    if (p >= 9 && threadIdx.x < 64) {
        int dt = p - 9;
        float s = 0.f;
        for (int r = 0; r < 9; ++r)
            if (rel_dt[r] == dt) s += wload(bl, (long)(l * 9 + r) * 64 + threadIdx.x, wf32);
        blsum[(l * 4 + dt) * 64 + threadIdx.x] = s;
    }
}

// ---------- consolidated CSR build ----------
struct EdgeArgs {
    const int* ei[9];
    long eoff[10];
    int cntoff[9];
    int srcbase[9];
};

// count + emit per-edge rank (coalesced)
__global__ void count_all(EdgeArgs ea, const unsigned int* __restrict__ flags,
                          int* __restrict__ cnt, int* __restrict__ rank) {
    long e = (long)blockIdx.x * 256 + threadIdx.x;
    if (e >= ea.eoff[9]) return;
    int r = 0;
    while (r < 8 && e >= ea.eoff[r + 1]) ++r;
    long el = e - ea.eoff[r];
    long E = ea.eoff[r + 1] - ea.eoff[r];
    bool is64 = (flags[0] == 0u);
    const int* ei = ea.ei[r];
    int dst = is64 ? ei[2 * E + 2 * el] : ei[E + el];
    rank[e] = atomicAdd(&cnt[ea.cntoff[r] + dst], 1);
}

// atomic-free fill: pos = row_ptr[dst] + rank[e]
__global__ void fill_all(EdgeArgs ea, const unsigned int* __restrict__ flags,
                         const int* __restrict__ row_ptr, const int* __restrict__ rank,
                         int* __restrict__ edge_src) {
    long e = (long)blockIdx.x * 256 + threadIdx.x;
    if (e >= ea.eoff[9]) return;
    int r = 0;
    while (r < 8 && e >= ea.eoff[r + 1]) ++r;
    long el = e - ea.eoff[r];
    long E = ea.eoff[r + 1] - ea.eoff[r];
    bool is64 = (flags[0] == 0u);
    const int* ei = ea.ei[r];
    int src, dst;
    if (is64) { src = ei[2 * el]; dst = ei[2 * E + 2 * el]; }
    else      { src = ei[el];     dst = ei[E + el]; }
    int pos = row_ptr[ea.cntoff[r] + dst] + rank[e];
    edge_src[pos] = ea.srcbase[r] + src;
}

__global__ void scan_bsum(const int* __restrict__ cnt, int n, int* __restrict__ bsums) {
    __shared__ int red[256];
    int i = blockIdx.x * 256 + threadIdx.x;
    red[threadIdx.x] = (i < n) ? cnt[i] : 0;
    __syncthreads();
    for (int s = 128; s; s >>= 1) {
        if (threadIdx.x < s) red[threadIdx.x] += red[threadIdx.x + s];
        __syncthreads();
    }
    if (threadIdx.x == 0) bsums[blockIdx.x] = red[0];
}

__global__ void scan_excl_single(int* __restrict__ data, int n) {
    __shared__ int buf[1024];
    __shared__ int carry_s;
    if (threadIdx.x == 0) carry_s = 0;
    __syncthreads();
    for (int base = 0; base < n; base += 1024) {
        int i = base + threadIdx.x;
        int v = (i < n) ? data[i] : 0;
        buf[threadIdx.x] = v;
        __syncthreads();
        for (int off = 1; off < 1024; off <<= 1) {
            int tv = (threadIdx.x >= off) ? buf[threadIdx.x - off] : 0;
            __syncthreads();
            buf[threadIdx.x] += tv;
            __syncthreads();
        }
        int incl = buf[threadIdx.x];
        int carry = carry_s;
        if (i < n) data[i] = carry + incl - v;
        __syncthreads();
        if (threadIdx.x == 1023) carry_s = carry + buf[1023];
        __syncthreads();
    }
}

__global__ void scan_rowptr(const int* __restrict__ cnt, const int* __restrict__ bsums,
                            int n, int* __restrict__ row_ptr) {
    __shared__ int buf[256];
    int i = blockIdx.x * 256 + threadIdx.x;
    int v = (i < n) ? cnt[i] : 0;
    buf[threadIdx.x] = v;
    __syncthreads();
    for (int off = 1; off < 256; off <<= 1) {
        int tv = (threadIdx.x >= off) ? buf[threadIdx.x - off] : 0;
        __syncthreads();
        buf[threadIdx.x] += tv;
        __syncthreads();
    }
    int excl = buf[threadIdx.x] - v + bsums[blockIdx.x];
    if (i < n) row_ptr[i] = excl;
    if (i == n - 1) row_ptr[n] = excl + v;
}

// ---------- gather-mean v2: half-wave (32 lanes) per 4 rows ----------
// Static 4-edge-per-row pipeline: 16 index loads (one epoch, L1-hot) then 16
// independent 256B row loads in flight per wave -> 4x the MLP of one-row-per-
// half-wave. Rows with degree>4 fall through to the unrolled runtime loop.
__global__ void gather_mean(const __hip_bfloat16* __restrict__ x,
                            const int* __restrict__ edge_src,
                            const int* __restrict__ row_ptr,
                            __hip_bfloat16* __restrict__ agg, int nrows) {
    int hw = blockIdx.x * 8 + (threadIdx.x >> 5);
    int lane = threadIdx.x & 31;
    int r0 = hw * 4;
    if (r0 >= nrows) return;
    const unsigned* xu = (const unsigned*)x;

    int rp[5];
    #pragma unroll
    for (int k = 0; k < 5; ++k) {
        int rr = r0 + k;
        if (rr > nrows) rr = nrows;
        rp[k] = row_ptr[rr];
    }

    float a0[4] = {0.f, 0.f, 0.f, 0.f}, a1[4] = {0.f, 0.f, 0.f, 0.f};

    // phase 1: indices (uniform per half-wave, independent, L1-friendly)
    int idx[4][4];
    #pragma unroll
    for (int k = 0; k < 4; ++k)
        #pragma unroll
        for (int j = 0; j < 4; ++j) {
            int ee = rp[k] + j;
            idx[k][j] = edge_src[(ee < rp[k + 1]) ? ee : 0];
        }
    // phase 2: row data (16 independent 256B loads; empty slots hit row 0, L1-hot)
    unsigned v[4][4];
    #pragma unroll
    for (int k = 0; k < 4; ++k)
        #pragma unroll
        for (int j = 0; j < 4; ++j) {
            int ok = (rp[k] + j < rp[k + 1]);
            v[k][j] = xu[(long)(ok ? idx[k][j] : 0) * 32 + lane];
        }
    // phase 3: predicated accumulate
    #pragma unroll
    for (int k = 0; k < 4; ++k)
        #pragma unroll
        for (int j = 0; j < 4; ++j) {
            int ok = (rp[k] + j < rp[k + 1]);
            a0[k] += ok ? blo(v[k][j]) : 0.f;
            a1[k] += ok ? bhi(v[k][j]) : 0.f;
        }

    // leftover edges (degree > 4 rows only: ~15% of rows)
    #pragma unroll
    for (int k = 0; k < 4; ++k) {
        int e = rp[k] + 4, t = rp[k + 1];
        for (; e + 8 <= t; e += 8) {
            int id[8];
            unsigned vv[8];
            #pragma unroll
            for (int u = 0; u < 8; ++u) id[u] = edge_src[e + u];
            #pragma unroll
            for (int u = 0; u < 8; ++u) vv[u] = xu[(long)id[u] * 32 + lane];
            #pragma unroll
            for (int u = 0; u < 8; ++u) { a0[k] += blo(vv[u]); a1[k] += bhi(vv[u]); }
        }
        for (; e < t; ++e) {
            unsigned vv = xu[(long)edge_src[e] * 32 + lane];
            a0[k] += blo(vv); a1[k] += bhi(vv);
        }
    }

    // store
    #pragma unroll
    for (int k = 0; k < 4; ++k) {
        int r = r0 + k;
        if (r < nrows) {
            int d = rp[k + 1] - rp[k];
            float inv = (d > 0) ? 1.0f / (float)d : 0.f;
            __hip_bfloat162 o;
            o.x = __float2bfloat16(a0[k] * inv);
            o.y = __float2bfloat16(a1[k] * inv);
            ((__hip_bfloat162*)agg)[(long)r * 32 + lane] = o;
        }
    }
}

// ---------- layer update: register-resident weights, direct-global A, no LDS ----------
// x[d,:] = relu( sum_p agg_p[d,:] @ Wl_p + x[d,:] @ Wsum + blsum ),  in place.
struct UpdArgs {
    long aggOff[4][3];
    int wtSlot[4][4];
    long dstBase[4];
    int nDst[4];
    int Rdt[4];
    int blsumOff[4];
    int btBase[5];
    int totalBT;
};

__global__ __launch_bounds__(256) void update_layer(
    __hip_bfloat16* __restrict__ x,
    const __hip_bfloat16* __restrict__ agg,
    const bf16_t* __restrict__ wt,
    const float* __restrict__ blsum,
    UpdArgs ua, int btPerBlk) {
    int wv = threadIdx.x >> 6;
    int lane = threadIdx.x & 63;
    int quad = lane >> 4, l16 = lane & 15;
    int bt0 = blockIdx.x * btPerBlk;
    int bt1 = bt0 + btPerBlk;
    if (bt1 > ua.totalBT) bt1 = ua.totalBT;
    int curdt = -1;
    bf16x8 B[4][4][2];   // [pass][nt][kc] — compile-time indexed only

    for (int bt = bt0; bt < bt1; ++bt) {
        int slot = 0;
        while (slot < 3 && bt >= ua.btBase[slot + 1]) ++slot;
        int dt = slot;
        int R = ua.Rdt[dt];
        if (dt != curdt) {
            curdt = dt;
            #pragma unroll
            for (int p = 0; p < 4; ++p) {
                if (p <= R) {
                    const bf16_t* wb = wt + (long)ua.wtSlot[dt][p == R ? 3 : p] * 4096;
                    #pragma unroll
                    for (int nt = 0; nt < 4; ++nt)
                        #pragma unroll
                        for (int kc = 0; kc < 2; ++kc)
                            B[p][nt][kc] = *(const bf16x8*)(wb + (nt * 16 + l16) * 64 + kc * 32 + quad * 8);
                }
            }
        }
        long d0 = (long)(bt - ua.btBase[slot]) * 64 + wv * 16;
        f32x4 acc[4] = {};
        #pragma unroll
        for (int p = 0; p < 4; ++p) {
            if (p <= R) {
                const bf16_t* abase = (p == R)
                    ? (const bf16_t*)x + (ua.dstBase[dt] + d0) * 64
                    : (const bf16_t*)agg + (ua.aggOff[dt][p == R ? 0 : p] + d0) * 64;
                bf16x8 a0 = *(const bf16x8*)(abase + l16 * 64 + quad * 8);
                bf16x8 a1 = *(const bf16x8*)(abase + l16 * 64 + 32 + quad * 8);
                #pragma unroll
                for (int nt = 0; nt < 4; ++nt) {
                    acc[nt] = __builtin_amdgcn_mfma_f32_16x16x32_bf16(a0, B[p][nt][0], acc[nt], 0, 0, 0);
                    acc[nt] = __builtin_amdgcn_mfma_f32_16x16x32_bf16(a1, B[p][nt][1], acc[nt], 0, 0, 0);
                }
            }
        }
        const float* bs = blsum + ua.blsumOff[dt];
        int n_dst = ua.nDst[dt];
        #pragma unroll
        for (int nt = 0; nt < 4; ++nt) {
            int col = nt * 16 + l16;
            float bv = bs[col];
            #pragma unroll
            for (int reg = 0; reg < 4; ++reg) {
                long dd = d0 + quad * 4 + reg;
                if (dd < n_dst)
                    x[(ua.dstBase[dt] + dd) * 64 + col] =
                        __float2bfloat16(fmaxf(acc[nt][reg] + bv, 0.f));
            }
        }
    }
}

// ---------- head: softplus(x@projW+projb) @ outW + outb ----------
__global__ __launch_bounds__(256) void head_k(
    const __hip_bfloat16* __restrict__ xc,
    const void* __restrict__ projW, const void* __restrict__ projb,
    const void* __restrict__ outW, const void* __restrict__ outb,
    void* __restrict__ out, const unsigned int* __restrict__ flags, int n) {
    __shared__ float PW[64 * 64];
    __shared__ float PB[64], OW[64];
    __shared__ float ROW[4][64];
    bool wf32 = flags[2] > 64;
    bool of32 = flags[1] > 64;
    int t = threadIdx.x;
    for (int i = t; i < 4096; i += 256) PW[i] = wload(projW, i, wf32);
    if (t < 64) { PB[t] = wload(projb, t, wf32); OW[t] = wload(outW, t, wf32); }
    int wid = t >> 6, lane = t & 63;
    int d = blockIdx.x * 4 + wid;
    ROW[wid][lane] = (d < n) ? __bfloat162float(xc[(long)d * H64 + lane]) : 0.f;
    __syncthreads();
    if (d < n) {
        float s = PB[lane];
        #pragma unroll 8
        for (int k = 0; k < 64; ++k) s += ROW[wid][k] * PW[k * 64 + lane];
        float sp = fmaxf(s, 0.f) + log1pf(expf(-fabsf(s)));
        float c = sp * OW[lane];
        #pragma unroll
        for (int off = 32; off; off >>= 1) c += __shfl_down(c, off, 64);
        if (lane == 0) {
            float rv = c + wload(outb, 0, wf32);
            if (of32) ((float*)out)[d] = rv;
            else ((__hip_bfloat16*)out)[d] = __float2bfloat16(rv);
        }
    }
}

extern "C" void kernel_launch(void* const* d_in, const int* in_sizes, int n_in,
                              void* d_out, int out_size, void* d_ws, size_t ws_size,
                              hipStream_t stream) {
    static const int rel_st[9] = {0, 0, 0, 1, 1, 2, 0, 1, 2};
    static const int rel_dt[9] = {0, 1, 2, 1, 2, 2, 3, 3, 3};
    static const int relsOf[4][3] = {{0, -1, -1}, {1, 3, -1}, {2, 4, 5}, {6, 7, 8}};
    static const int Rof[4] = {1, 2, 3, 3};

    long rows[4], rowoff[4], total = 0;
    for (int t = 0; t < 4; ++t) { rows[t] = in_sizes[t] / H64; rowoff[t] = total; total += rows[t]; }
    long NX = total * H64;
    long Es[9], ET = 0;
    for (int r = 0; r < 9; ++r) { Es[r] = (long)in_sizes[11 + r] / 2; ET += Es[r]; }
    long cntoff[9], cntN = 0;
    for (int r = 0; r < 9; ++r) { cntoff[r] = cntN; cntN += rows[rel_dt[r]]; }
    long nb1 = (cntN + 255) / 256;

    unsigned int* flags = (unsigned int*)d_ws;
    char* wsbase = (char*)d_ws + 64;
    auto align16 = [](size_t v) { return (v + 15) & ~(size_t)15; };
    size_t off = 0;
    __hip_bfloat16* x = (__hip_bfloat16*)(wsbase + off);   off = align16(off + (size_t)NX * 2);
    __hip_bfloat16* agg = (__hip_bfloat16*)(wsbase + off); off = align16(off + (size_t)cntN * H64 * 2);
    int* cnt_i = (int*)(wsbase + off);                     off = align16(off + (size_t)cntN * 4);
    int* row_ptr = (int*)(wsbase + off);                   off = align16(off + (size_t)(cntN + 1) * 4);
    int* rank = (int*)(wsbase + off);                      off = align16(off + (size_t)ET * 4);
    int* edge_src = (int*)(wsbase + off);                  off = align16(off + (size_t)ET * 4);
    int* bsums = (int*)(wsbase + off);                     off = align16(off + (size_t)nb1 * 4);
    bf16_t* wt = (bf16_t*)(wsbase + off);                  off = align16(off + (size_t)39 * 4096 * 2);
    float* blsum = (float*)(wsbase + off);                 off = align16(off + (size_t)12 * 64 * 4);

    // format detection
    hipMemsetAsync(d_ws, 0, 64, stream);
    int nwords = 16384;
    if (in_sizes[11] < nwords) nwords = in_sizes[11];
    detect_k<<<1, 256, 0, stream>>>((const unsigned int*)d_in[11], nwords,
                                    (const unsigned short*)d_in[0],
                                    (const unsigned short*)d_in[4], flags);

    // x inputs -> bf16 ws (single dispatch)
    ConvArgs ca;
    for (int t = 0; t < 4; ++t) { ca.src[t] = d_in[t]; ca.elemoff[t] = rowoff[t] * H64; }
    ca.elemoff[4] = NX;
    {
        int blocks = (int)((NX + 255) / 256); if (blocks > 8192) blocks = 8192;
        conv_in_all<<<blocks, 256, 0, stream>>>(ca, x, flags);
    }

    // weight prep (transpose + pre-sum, bf16)
    prep_w<<<39, 256, 0, stream>>>(d_in[4], d_in[6], d_in[5], flags, wt, blsum);

    // CSR build (edge structure is layer-invariant)
    EdgeArgs ea;
    long ecum = 0;
    for (int r = 0; r < 9; ++r) {
        ea.ei[r] = (const int*)d_in[11 + r];
        ea.eoff[r] = ecum; ecum += Es[r];
        ea.cntoff[r] = (int)cntoff[r];
        ea.srcbase[r] = (int)rowoff[rel_st[r]];
    }
    ea.eoff[9] = ecum;

    hipMemsetAsync(cnt_i, 0, (size_t)cntN * 4, stream);
    count_all<<<(int)((ET + 255) / 256), 256, 0, stream>>>(ea, flags, cnt_i, rank);
    scan_bsum<<<(int)nb1, 256, 0, stream>>>(cnt_i, (int)cntN, bsums);
    scan_excl_single<<<1, 1024, 0, stream>>>(bsums, (int)nb1);
    scan_rowptr<<<(int)nb1, 256, 0, stream>>>(cnt_i, bsums, (int)cntN, row_ptr);
    fill_all<<<(int)((ET + 255) / 256), 256, 0, stream>>>(ea, flags, row_ptr, rank, edge_src);

    // update-layer argument block (layer-invariant parts)
    UpdArgs ua;
    int bb = 0;
    for (int dt = 0; dt < 4; ++dt) {
        ua.nDst[dt] = (int)rows[dt];
        ua.Rdt[dt] = Rof[dt];
        ua.dstBase[dt] = rowoff[dt];
        ua.btBase[dt] = bb;
        bb += (int)((rows[dt] + 63) / 64);
        for (int p = 0; p < 3; ++p) {
            int rr = (p < Rof[dt]) ? relsOf[dt][p] : relsOf[dt][0];
            ua.aggOff[dt][p] = cntoff[rr];
        }
    }
    ua.btBase[4] = bb;
    ua.totalBT = bb;
    int btPerBlk = (bb + 1023) / 1024;
    if (btPerBlk < 1) btPerBlk = 1;
    int updGrid = (bb + btPerBlk - 1) / btPerBlk;

    // layers: gather (x -> agg), then in-place MFMA update
    for (int l = 0; l < 3; ++l) {
        gather_mean<<<(int)((cntN + 31) / 32), 256, 0, stream>>>(
            x, edge_src, row_ptr, agg, (int)cntN);
        for (int dt = 0; dt < 4; ++dt) {
            ua.blsumOff[dt] = (l * 4 + dt) * 64;
            for (int p = 0; p < 3; ++p) {
                int rr = (p < Rof[dt]) ? relsOf[dt][p] : relsOf[dt][0];
                ua.wtSlot[dt][p] = l * 13 + rr;
            }
            ua.wtSlot[dt][3] = l * 13 + 9 + dt;
        }
        update_layer<<<updGrid, 256, 0, stream>>>(x, agg, wt, blsum, ua, btPerBlk);
    }

    head_k<<<(int)((rows[3] + 3) / 4), 256, 0, stream>>>(
        x + rowoff[3] * H64, d_in[7], d_in[8], d_in[9], d_in[10], d_out, flags, (int)rows[3]);
}

// Round 3
// 944.821 us; speedup vs baseline: 1.0767x; 1.0167x over previous
//
#include <hip/hip_runtime.h>
#include <hip/hip_bf16.h>

#define H64 64

typedef __bf16 bf16_t;
typedef __bf16 bf16x8 __attribute__((ext_vector_type(8)));
typedef float f32x4 __attribute__((ext_vector_type(4)));

// ---------- helpers ----------
__device__ __forceinline__ float wload(const void* p, long i, bool f32) {
    return f32 ? ((const float*)p)[i]
               : __bfloat162float(((const __hip_bfloat16*)p)[i]);
}
__device__ __forceinline__ float blo(unsigned v) { return __uint_as_float(v << 16); }
__device__ __forceinline__ float bhi(unsigned v) { return __uint_as_float(v & 0xffff0000u); }

// ---------- runtime format detection ----------
// flags[0] != 0 -> edge indices int32 (odd words nonzero); ==0 -> int64
// flags[1] > 64 -> x tensors f32; else bf16.  flags[2] > 64 -> weights f32.
__global__ void detect_k(const unsigned int* __restrict__ eiw, int nwords,
                         const unsigned short* __restrict__ xw,
                         const unsigned short* __restrict__ ww,
                         unsigned int* __restrict__ flags) {
    int t = threadIdx.x;
    unsigned int acc = 0;
    for (int i = 1 + 2 * t; i < nwords; i += 512) acc |= eiw[i];
    if (acc) atomicOr(&flags[0], acc);
    unsigned int cx = 0, cw = 0;
    for (int i = t; i < 8192; i += 256) {
        unsigned short w = xw[i];
        unsigned int e = (w >> 7) & 0xFF;
        if ((w & 0x7FFF) && (e == 0xFF || e < 0x40)) cx++;
        w = ww[i];
        e = (w >> 7) & 0xFF;
        if ((w & 0x7FFF) && (e == 0xFF || e < 0x40)) cw++;
    }
    if (cx) atomicAdd(&flags[1], cx);
    if (cw) atomicAdd(&flags[2], cw);
}

// ---------- convert all x inputs -> bf16 ws storage (single dispatch) ----------
struct ConvArgs {
    const void* src[4];
    long elemoff[5];   // element offsets (rows*64) per type, cumulative
};
__global__ void conv_in_all(ConvArgs ca, __hip_bfloat16* __restrict__ dst,
                            const unsigned int* __restrict__ flags) {
    bool xf32 = flags[1] > 64;
    long n = ca.elemoff[4];
    long i = (long)blockIdx.x * blockDim.x + threadIdx.x;
    long stride = (long)gridDim.x * blockDim.x;
    for (; i < n; i += stride) {
        int t = (i >= ca.elemoff[2]) ? (i >= ca.elemoff[3] ? 3 : 2)
                                     : (i >= ca.elemoff[1] ? 1 : 0);
        long j = i - ca.elemoff[t];
        float v = xf32 ? ((const float*)ca.src[t])[j]
                       : __bfloat162float(((const __hip_bfloat16*)ca.src[t])[j]);
        dst[i] = __float2bfloat16(v);
    }
}

// ---------- weight prep: bf16, transposed WT[n][k]; Wr pre-summed per (l,dt) ----------
// blockIdx.x = l*13 + p.  p<9: WT of Wl[l,p].  p in 9..12: dt=p-9, WT of sum(Wr) + blsum.
__global__ void prep_w(const void* __restrict__ Wl, const void* __restrict__ Wr,
                       const void* __restrict__ bl, const unsigned int* __restrict__ flags,
                       bf16_t* __restrict__ wt, float* __restrict__ blsum) {
    const int rel_dt[9] = {0, 1, 2, 1, 2, 2, 3, 3, 3};
    bool wf32 = flags[2] > 64;
    int l = blockIdx.x / 13, p = blockIdx.x % 13;
    bf16_t* dst = wt + (long)blockIdx.x * 4096;
    for (int i = threadIdx.x; i < 4096; i += 256) {
        int n = i >> 6, k = i & 63;
        float v;
        if (p < 9) {
            v = wload(Wl, (long)(l * 9 + p) * 4096 + k * 64 + n, wf32);
        } else {
            int dt = p - 9;
            v = 0.f;
            for (int r = 0; r < 9; ++r)
                if (rel_dt[r] == dt) v += wload(Wr, (long)(l * 9 + r) * 4096 + k * 64 + n, wf32);
        }
        __hip_bfloat16 h = __float2bfloat16(v);
        dst[i] = *(bf16_t*)&h;
    }
    if (p >= 9 && threadIdx.x < 64) {
        int dt = p - 9;
        float s = 0.f;
        for (int r = 0; r < 9; ++r)
            if (rel_dt[r] == dt) s += wload(bl, (long)(l * 9 + r) * 64 + threadIdx.x, wf32);
        blsum[(l * 4 + dt) * 64 + threadIdx.x] = s;
    }
}

// ---------- consolidated CSR build ----------
struct EdgeArgs {
    const int* ei[9];
    long eoff[10];
    int cntoff[9];
    int srcbase[9];
};

// count + emit per-edge rank (coalesced)
__global__ void count_all(EdgeArgs ea, const unsigned int* __restrict__ flags,
                          int* __restrict__ cnt, int* __restrict__ rank) {
    long e = (long)blockIdx.x * 256 + threadIdx.x;
    if (e >= ea.eoff[9]) return;
    int r = 0;
    while (r < 8 && e >= ea.eoff[r + 1]) ++r;
    long el = e - ea.eoff[r];
    long E = ea.eoff[r + 1] - ea.eoff[r];
    bool is64 = (flags[0] == 0u);
    const int* ei = ea.ei[r];
    int dst = is64 ? ei[2 * E + 2 * el] : ei[E + el];
    rank[e] = atomicAdd(&cnt[ea.cntoff[r] + dst], 1);
}

// atomic-free fill: pos = row_ptr[dst] + rank[e]
__global__ void fill_all(EdgeArgs ea, const unsigned int* __restrict__ flags,
                         const int* __restrict__ row_ptr, const int* __restrict__ rank,
                         int* __restrict__ edge_src) {
    long e = (long)blockIdx.x * 256 + threadIdx.x;
    if (e >= ea.eoff[9]) return;
    int r = 0;
    while (r < 8 && e >= ea.eoff[r + 1]) ++r;
    long el = e - ea.eoff[r];
    long E = ea.eoff[r + 1] - ea.eoff[r];
    bool is64 = (flags[0] == 0u);
    const int* ei = ea.ei[r];
    int src, dst;
    if (is64) { src = ei[2 * el]; dst = ei[2 * E + 2 * el]; }
    else      { src = ei[el];     dst = ei[E + el]; }
    int pos = row_ptr[ea.cntoff[r] + dst] + rank[e];
    edge_src[pos] = ea.srcbase[r] + src;
}

__global__ void scan_bsum(const int* __restrict__ cnt, int n, int* __restrict__ bsums) {
    __shared__ int red[256];
    int i = blockIdx.x * 256 + threadIdx.x;
    red[threadIdx.x] = (i < n) ? cnt[i] : 0;
    __syncthreads();
    for (int s = 128; s; s >>= 1) {
        if (threadIdx.x < s) red[threadIdx.x] += red[threadIdx.x + s];
        __syncthreads();
    }
    if (threadIdx.x == 0) bsums[blockIdx.x] = red[0];
}

__global__ void scan_excl_single(int* __restrict__ data, int n) {
    __shared__ int buf[1024];
    __shared__ int carry_s;
    if (threadIdx.x == 0) carry_s = 0;
    __syncthreads();
    for (int base = 0; base < n; base += 1024) {
        int i = base + threadIdx.x;
        int v = (i < n) ? data[i] : 0;
        buf[threadIdx.x] = v;
        __syncthreads();
        for (int off = 1; off < 1024; off <<= 1) {
            int tv = (threadIdx.x >= off) ? buf[threadIdx.x - off] : 0;
            __syncthreads();
            buf[threadIdx.x] += tv;
            __syncthreads();
        }
        int incl = buf[threadIdx.x];
        int carry = carry_s;
        if (i < n) data[i] = carry + incl - v;
        __syncthreads();
        if (threadIdx.x == 1023) carry_s = carry + buf[1023];
        __syncthreads();
    }
}

__global__ void scan_rowptr(const int* __restrict__ cnt, const int* __restrict__ bsums,
                            int n, int* __restrict__ row_ptr) {
    __shared__ int buf[256];
    int i = blockIdx.x * 256 + threadIdx.x;
    int v = (i < n) ? cnt[i] : 0;
    buf[threadIdx.x] = v;
    __syncthreads();
    for (int off = 1; off < 256; off <<= 1) {
        int tv = (threadIdx.x >= off) ? buf[threadIdx.x - off] : 0;
        __syncthreads();
        buf[threadIdx.x] += tv;
        __syncthreads();
    }
    int excl = buf[threadIdx.x] - v + bsums[blockIdx.x];
    if (i < n) row_ptr[i] = excl;
    if (i == n - 1) row_ptr[n] = excl + v;
}

// ---------- gather-mean v3: quarter-wave (16 lanes x uint2) per 4 rows ----------
// One wave instruction covers 4 rows (vs 2 for half-wave/dword): halves VMEM
// instruction count and per-edge VALU. 32-bit address math (x fits u32 range).
__global__ void gather_mean(const __hip_bfloat16* __restrict__ x,
                            const int* __restrict__ edge_src,
                            const int* __restrict__ row_ptr,
                            __hip_bfloat16* __restrict__ agg, int nrows) {
    int qw = blockIdx.x * 16 + (threadIdx.x >> 4);
    int l16 = threadIdx.x & 15;
    int r0 = qw * 4;
    if (r0 >= nrows) return;
    const uint2* xu = (const uint2*)x;   // one row = 16 uint2 (128B)

    int rp[5];
    #pragma unroll
    for (int k = 0; k < 5; ++k) {
        int rr = r0 + k;
        if (rr > nrows) rr = nrows;
        rp[k] = row_ptr[rr];
    }

    // phase 1: indices (uniform per quarter-wave, independent, L1-friendly)
    int idx[4][4];
    #pragma unroll
    for (int k = 0; k < 4; ++k)
        #pragma unroll
        for (int j = 0; j < 4; ++j) {
            int ee = rp[k] + j;
            idx[k][j] = edge_src[(ee < rp[k + 1]) ? ee : 0];
        }
    // phase 2: row data (16 independent 128B row loads in flight, u32 offsets)
    uint2 v[4][4];
    #pragma unroll
    for (int k = 0; k < 4; ++k)
        #pragma unroll
        for (int j = 0; j < 4; ++j)
            v[k][j] = xu[(unsigned)idx[k][j] * 16u + (unsigned)l16];
    // phase 3: zero invalid slots (2 cndmask) + accumulate 4 f32 per row
    float a0[4] = {0.f, 0.f, 0.f, 0.f}, a1[4] = {0.f, 0.f, 0.f, 0.f};
    float a2[4] = {0.f, 0.f, 0.f, 0.f}, a3[4] = {0.f, 0.f, 0.f, 0.f};
    #pragma unroll
    for (int k = 0; k < 4; ++k)
        #pragma unroll
        for (int j = 0; j < 4; ++j) {
            bool ok = (rp[k] + j < rp[k + 1]);
            unsigned d0 = ok ? v[k][j].x : 0u;
            unsigned d1 = ok ? v[k][j].y : 0u;
            a0[k] += blo(d0); a1[k] += bhi(d0);
            a2[k] += blo(d1); a3[k] += bhi(d1);
        }

    // leftover edges (degree > 4 rows)
    #pragma unroll
    for (int k = 0; k < 4; ++k) {
        int e = rp[k] + 4, t = rp[k + 1];
        for (; e + 8 <= t; e += 8) {
            int id[8];
            uint2 vv[8];
            #pragma unroll
            for (int u = 0; u < 8; ++u) id[u] = edge_src[e + u];
            #pragma unroll
            for (int u = 0; u < 8; ++u) vv[u] = xu[(unsigned)id[u] * 16u + (unsigned)l16];
            #pragma unroll
            for (int u = 0; u < 8; ++u) {
                a0[k] += blo(vv[u].x); a1[k] += bhi(vv[u].x);
                a2[k] += blo(vv[u].y); a3[k] += bhi(vv[u].y);
            }
        }
        for (; e < t; ++e) {
            uint2 vv = xu[(unsigned)edge_src[e] * 16u + (unsigned)l16];
            a0[k] += blo(vv.x); a1[k] += bhi(vv.x);
            a2[k] += blo(vv.y); a3[k] += bhi(vv.y);
        }
    }

    // store (uint2 per lane = 128B per row across quarter-wave)
    #pragma unroll
    for (int k = 0; k < 4; ++k) {
        int r = r0 + k;
        if (r < nrows) {
            int d = rp[k + 1] - rp[k];
            float inv = (d > 0) ? 1.0f / (float)d : 0.f;
            __hip_bfloat162 lo, hi;
            lo.x = __float2bfloat16(a0[k] * inv);
            lo.y = __float2bfloat16(a1[k] * inv);
            hi.x = __float2bfloat16(a2[k] * inv);
            hi.y = __float2bfloat16(a3[k] * inv);
            uint2 o;
            o.x = *(unsigned*)&lo;
            o.y = *(unsigned*)&hi;
            ((uint2*)agg)[(unsigned)r * 16u + (unsigned)l16] = o;
        }
    }
}

// ---------- layer update: register-resident weights, direct-global A, no LDS ----------
// x[d,:] = relu( sum_p agg_p[d,:] @ Wl_p + x[d,:] @ Wsum + blsum ),  in place.
struct UpdArgs {
    long aggOff[4][3];
    int wtSlot[4][4];
    long dstBase[4];
    int nDst[4];
    int Rdt[4];
    int blsumOff[4];
    int btBase[5];
    int totalBT;
};

__global__ __launch_bounds__(256) void update_layer(
    __hip_bfloat16* __restrict__ x,
    const __hip_bfloat16* __restrict__ agg,
    const bf16_t* __restrict__ wt,
    const float* __restrict__ blsum,
    UpdArgs ua, int btPerBlk) {
    int wv = threadIdx.x >> 6;
    int lane = threadIdx.x & 63;
    int quad = lane >> 4, l16 = lane & 15;
    int bt0 = blockIdx.x * btPerBlk;
    int bt1 = bt0 + btPerBlk;
    if (bt1 > ua.totalBT) bt1 = ua.totalBT;
    int curdt = -1;
    bf16x8 B[4][4][2];   // [pass][nt][kc] — compile-time indexed only

    for (int bt = bt0; bt < bt1; ++bt) {
        int slot = 0;
        while (slot < 3 && bt >= ua.btBase[slot + 1]) ++slot;
        int dt = slot;
        int R = ua.Rdt[dt];
        if (dt != curdt) {
            curdt = dt;
            #pragma unroll
            for (int p = 0; p < 4; ++p) {
                if (p <= R) {
                    const bf16_t* wb = wt + (long)ua.wtSlot[dt][p == R ? 3 : p] * 4096;
                    #pragma unroll
                    for (int nt = 0; nt < 4; ++nt)
                        #pragma unroll
                        for (int kc = 0; kc < 2; ++kc)
                            B[p][nt][kc] = *(const bf16x8*)(wb + (nt * 16 + l16) * 64 + kc * 32 + quad * 8);
                }
            }
        }
        long d0 = (long)(bt - ua.btBase[slot]) * 64 + wv * 16;
        f32x4 acc[4] = {};
        #pragma unroll
        for (int p = 0; p < 4; ++p) {
            if (p <= R) {
                const bf16_t* abase = (p == R)
                    ? (const bf16_t*)x + (ua.dstBase[dt] + d0) * 64
                    : (const bf16_t*)agg + (ua.aggOff[dt][p == R ? 0 : p] + d0) * 64;
                bf16x8 a0 = *(const bf16x8*)(abase + l16 * 64 + quad * 8);
                bf16x8 a1 = *(const bf16x8*)(abase + l16 * 64 + 32 + quad * 8);
                #pragma unroll
                for (int nt = 0; nt < 4; ++nt) {
                    acc[nt] = __builtin_amdgcn_mfma_f32_16x16x32_bf16(a0, B[p][nt][0], acc[nt], 0, 0, 0);
                    acc[nt] = __builtin_amdgcn_mfma_f32_16x16x32_bf16(a1, B[p][nt][1], acc[nt], 0, 0, 0);
                }
            }
        }
        const float* bs = blsum + ua.blsumOff[dt];
        int n_dst = ua.nDst[dt];
        #pragma unroll
        for (int nt = 0; nt < 4; ++nt) {
            int col = nt * 16 + l16;
            float bv = bs[col];
            #pragma unroll
            for (int reg = 0; reg < 4; ++reg) {
                long dd = d0 + quad * 4 + reg;
                if (dd < n_dst)
                    x[(ua.dstBase[dt] + dd) * 64 + col] =
                        __float2bfloat16(fmaxf(acc[nt][reg] + bv, 0.f));
            }
        }
    }
}

// ---------- head: softplus(x@projW+projb) @ outW + outb ----------
__global__ __launch_bounds__(256) void head_k(
    const __hip_bfloat16* __restrict__ xc,
    const void* __restrict__ projW, const void* __restrict__ projb,
    const void* __restrict__ outW, const void* __restrict__ outb,
    void* __restrict__ out, const unsigned int* __restrict__ flags, int n) {
    __shared__ float PW[64 * 64];
    __shared__ float PB[64], OW[64];
    __shared__ float ROW[4][64];
    bool wf32 = flags[2] > 64;
    bool of32 = flags[1] > 64;
    int t = threadIdx.x;
    for (int i = t; i < 4096; i += 256) PW[i] = wload(projW, i, wf32);
    if (t < 64) { PB[t] = wload(projb, t, wf32); OW[t] = wload(outW, t, wf32); }
    int wid = t >> 6, lane = t & 63;
    int d = blockIdx.x * 4 + wid;
    ROW[wid][lane] = (d < n) ? __bfloat162float(xc[(long)d * H64 + lane]) : 0.f;
    __syncthreads();
    if (d < n) {
        float s = PB[lane];
        #pragma unroll 8
        for (int k = 0; k < 64; ++k) s += ROW[wid][k] * PW[k * 64 + lane];
        float sp = fmaxf(s, 0.f) + log1pf(expf(-fabsf(s)));
        float c = sp * OW[lane];
        #pragma unroll
        for (int off = 32; off; off >>= 1) c += __shfl_down(c, off, 64);
        if (lane == 0) {
            float rv = c + wload(outb, 0, wf32);
            if (of32) ((float*)out)[d] = rv;
            else ((__hip_bfloat16*)out)[d] = __float2bfloat16(rv);
        }
    }
}

extern "C" void kernel_launch(void* const* d_in, const int* in_sizes, int n_in,
                              void* d_out, int out_size, void* d_ws, size_t ws_size,
                              hipStream_t stream) {
    static const int rel_st[9] = {0, 0, 0, 1, 1, 2, 0, 1, 2};
    static const int rel_dt[9] = {0, 1, 2, 1, 2, 2, 3, 3, 3};
    static const int relsOf[4][3] = {{0, -1, -1}, {1, 3, -1}, {2, 4, 5}, {6, 7, 8}};
    static const int Rof[4] = {1, 2, 3, 3};

    long rows[4], rowoff[4], total = 0;
    for (int t = 0; t < 4; ++t) { rows[t] = in_sizes[t] / H64; rowoff[t] = total; total += rows[t]; }
    long NX = total * H64;
    long Es[9], ET = 0;
    for (int r = 0; r < 9; ++r) { Es[r] = (long)in_sizes[11 + r] / 2; ET += Es[r]; }
    long cntoff[9], cntN = 0;
    for (int r = 0; r < 9; ++r) { cntoff[r] = cntN; cntN += rows[rel_dt[r]]; }
    long nb1 = (cntN + 255) / 256;

    unsigned int* flags = (unsigned int*)d_ws;
    char* wsbase = (char*)d_ws + 64;
    auto align16 = [](size_t v) { return (v + 15) & ~(size_t)15; };
    size_t off = 0;
    __hip_bfloat16* x = (__hip_bfloat16*)(wsbase + off);   off = align16(off + (size_t)NX * 2);
    __hip_bfloat16* agg = (__hip_bfloat16*)(wsbase + off); off = align16(off + (size_t)cntN * H64 * 2);
    int* cnt_i = (int*)(wsbase + off);                     off = align16(off + (size_t)cntN * 4);
    int* row_ptr = (int*)(wsbase + off);                   off = align16(off + (size_t)(cntN + 1) * 4);
    int* rank = (int*)(wsbase + off);                      off = align16(off + (size_t)ET * 4);
    int* edge_src = (int*)(wsbase + off);                  off = align16(off + (size_t)ET * 4);
    int* bsums = (int*)(wsbase + off);                     off = align16(off + (size_t)nb1 * 4);
    bf16_t* wt = (bf16_t*)(wsbase + off);                  off = align16(off + (size_t)39 * 4096 * 2);
    float* blsum = (float*)(wsbase + off);                 off = align16(off + (size_t)12 * 64 * 4);

    // format detection
    hipMemsetAsync(d_ws, 0, 64, stream);
    int nwords = 16384;
    if (in_sizes[11] < nwords) nwords = in_sizes[11];
    detect_k<<<1, 256, 0, stream>>>((const unsigned int*)d_in[11], nwords,
                                    (const unsigned short*)d_in[0],
                                    (const unsigned short*)d_in[4], flags);

    // x inputs -> bf16 ws (single dispatch)
    ConvArgs ca;
    for (int t = 0; t < 4; ++t) { ca.src[t] = d_in[t]; ca.elemoff[t] = rowoff[t] * H64; }
    ca.elemoff[4] = NX;
    {
        int blocks = (int)((NX + 255) / 256); if (blocks > 8192) blocks = 8192;
        conv_in_all<<<blocks, 256, 0, stream>>>(ca, x, flags);
    }

    // weight prep (transpose + pre-sum, bf16)
    prep_w<<<39, 256, 0, stream>>>(d_in[4], d_in[6], d_in[5], flags, wt, blsum);

    // CSR build (edge structure is layer-invariant)
    EdgeArgs ea;
    long ecum = 0;
    for (int r = 0; r < 9; ++r) {
        ea.ei[r] = (const int*)d_in[11 + r];
        ea.eoff[r] = ecum; ecum += Es[r];
        ea.cntoff[r] = (int)cntoff[r];
        ea.srcbase[r] = (int)rowoff[rel_st[r]];
    }
    ea.eoff[9] = ecum;

    hipMemsetAsync(cnt_i, 0, (size_t)cntN * 4, stream);
    count_all<<<(int)((ET + 255) / 256), 256, 0, stream>>>(ea, flags, cnt_i, rank);
    scan_bsum<<<(int)nb1, 256, 0, stream>>>(cnt_i, (int)cntN, bsums);
    scan_excl_single<<<1, 1024, 0, stream>>>(bsums, (int)nb1);
    scan_rowptr<<<(int)nb1, 256, 0, stream>>>(cnt_i, bsums, (int)cntN, row_ptr);
    fill_all<<<(int)((ET + 255) / 256), 256, 0, stream>>>(ea, flags, row_ptr, rank, edge_src);

    // update-layer argument block (layer-invariant parts)
    UpdArgs ua;
    int bb = 0;
    for (int dt = 0; dt < 4; ++dt) {
        ua.nDst[dt] = (int)rows[dt];
        ua.Rdt[dt] = Rof[dt];
        ua.dstBase[dt] = rowoff[dt];
        ua.btBase[dt] = bb;
        bb += (int)((rows[dt] + 63) / 64);
        for (int p = 0; p < 3; ++p) {
            int rr = (p < Rof[dt]) ? relsOf[dt][p] : relsOf[dt][0];
            ua.aggOff[dt][p] = cntoff[rr];
        }
    }
    ua.btBase[4] = bb;
    ua.totalBT = bb;
    int btPerBlk = (bb + 1023) / 1024;
    if (btPerBlk < 1) btPerBlk = 1;
    int updGrid = (bb + btPerBlk - 1) / btPerBlk;

    // layers: gather (x -> agg), then in-place MFMA update
    for (int l = 0; l < 3; ++l) {
        gather_mean<<<(int)((cntN + 63) / 64), 256, 0, stream>>>(
            x, edge_src, row_ptr, agg, (int)cntN);
        for (int dt = 0; dt < 4; ++dt) {
            ua.blsumOff[dt] = (l * 4 + dt) * 64;
            for (int p = 0; p < 3; ++p) {
                int rr = (p < Rof[dt]) ? relsOf[dt][p] : relsOf[dt][0];
                ua.wtSlot[dt][p] = l * 13 + rr;
            }
            ua.wtSlot[dt][3] = l * 13 + 9 + dt;
        }
        update_layer<<<updGrid, 256, 0, stream>>>(x, agg, wt, blsum, ua, btPerBlk);
    }

    head_k<<<(int)((rows[3] + 3) / 4), 256, 0, stream>>>(
        x + rowoff[3] * H64, d_in[7], d_in[8], d_in[9], d_in[10], d_out, flags, (int)rows[3]);
}

// Round 4
// 883.093 us; speedup vs baseline: 1.1520x; 1.0699x over previous
//
#include <hip/hip_runtime.h>
#include <hip/hip_bf16.h>

#define H64 64

typedef __bf16 bf16_t;
typedef __bf16 bf16x8 __attribute__((ext_vector_type(8)));
typedef float f32x4 __attribute__((ext_vector_type(4)));

// ---------- helpers ----------
__device__ __forceinline__ float wload(const void* p, long i, bool f32) {
    return f32 ? ((const float*)p)[i]
               : __bfloat162float(((const __hip_bfloat16*)p)[i]);
}
__device__ __forceinline__ float blo(unsigned v) { return __uint_as_float(v << 16); }
__device__ __forceinline__ float bhi(unsigned v) { return __uint_as_float(v & 0xffff0000u); }
__device__ __forceinline__ unsigned packbf(float lo, float hi) {
    __hip_bfloat162 t;
    t.x = __float2bfloat16(lo);
    t.y = __float2bfloat16(hi);
    return *(unsigned*)&t;
}
__device__ __forceinline__ void acc8(float* s, uint4 v, unsigned m) {
    s[0] += blo(v.x & m); s[1] += bhi(v.x & m);
    s[2] += blo(v.y & m); s[3] += bhi(v.y & m);
    s[4] += blo(v.z & m); s[5] += bhi(v.z & m);
    s[6] += blo(v.w & m); s[7] += bhi(v.w & m);
}

// ---------- runtime format detection ----------
// flags[0] != 0 -> edge indices int32 (odd words nonzero); ==0 -> int64
// flags[1] > 64 -> x tensors f32; else bf16.  flags[2] > 64 -> weights f32.
__global__ void detect_k(const unsigned int* __restrict__ eiw, int nwords,
                         const unsigned short* __restrict__ xw,
                         const unsigned short* __restrict__ ww,
                         unsigned int* __restrict__ flags) {
    int t = threadIdx.x;
    unsigned int acc = 0;
    for (int i = 1 + 2 * t; i < nwords; i += 512) acc |= eiw[i];
    if (acc) atomicOr(&flags[0], acc);
    unsigned int cx = 0, cw = 0;
    for (int i = t; i < 8192; i += 256) {
        unsigned short w = xw[i];
        unsigned int e = (w >> 7) & 0xFF;
        if ((w & 0x7FFF) && (e == 0xFF || e < 0x40)) cx++;
        w = ww[i];
        e = (w >> 7) & 0xFF;
        if ((w & 0x7FFF) && (e == 0xFF || e < 0x40)) cw++;
    }
    if (cx) atomicAdd(&flags[1], cx);
    if (cw) atomicAdd(&flags[2], cw);
}

// ---------- convert all x inputs -> bf16 ws storage (single dispatch) ----------
struct ConvArgs {
    const void* src[4];
    long elemoff[5];   // element offsets (rows*64) per type, cumulative
};
__global__ void conv_in_all(ConvArgs ca, __hip_bfloat16* __restrict__ dst,
                            const unsigned int* __restrict__ flags) {
    bool xf32 = flags[1] > 64;
    long n = ca.elemoff[4];
    long i = (long)blockIdx.x * blockDim.x + threadIdx.x;
    long stride = (long)gridDim.x * blockDim.x;
    for (; i < n; i += stride) {
        int t = (i >= ca.elemoff[2]) ? (i >= ca.elemoff[3] ? 3 : 2)
                                     : (i >= ca.elemoff[1] ? 1 : 0);
        long j = i - ca.elemoff[t];
        float v = xf32 ? ((const float*)ca.src[t])[j]
                       : __bfloat162float(((const __hip_bfloat16*)ca.src[t])[j]);
        dst[i] = __float2bfloat16(v);
    }
}

// ---------- weight prep: bf16, transposed WT[n][k]; Wr pre-summed per (l,dt) ----------
// blockIdx.x = l*13 + p.  p<9: WT of Wl[l,p].  p in 9..12: dt=p-9, WT of sum(Wr) + blsum.
__global__ void prep_w(const void* __restrict__ Wl, const void* __restrict__ Wr,
                       const void* __restrict__ bl, const unsigned int* __restrict__ flags,
                       bf16_t* __restrict__ wt, float* __restrict__ blsum) {
    const int rel_dt[9] = {0, 1, 2, 1, 2, 2, 3, 3, 3};
    bool wf32 = flags[2] > 64;
    int l = blockIdx.x / 13, p = blockIdx.x % 13;
    bf16_t* dst = wt + (long)blockIdx.x * 4096;
    for (int i = threadIdx.x; i < 4096; i += 256) {
        int n = i >> 6, k = i & 63;
        float v;
        if (p < 9) {
            v = wload(Wl, (long)(l * 9 + p) * 4096 + k * 64 + n, wf32);
        } else {
            int dt = p - 9;
            v = 0.f;
            for (int r = 0; r < 9; ++r)
                if (rel_dt[r] == dt) v += wload(Wr, (long)(l * 9 + r) * 4096 + k * 64 + n, wf32);
        }
        __hip_bfloat16 h = __float2bfloat16(v);
        dst[i] = *(bf16_t*)&h;
    }
    if (p >= 9 && threadIdx.x < 64) {
        int dt = p - 9;
        float s = 0.f;
        for (int r = 0; r < 9; ++r)
            if (rel_dt[r] == dt) s += wload(bl, (long)(l * 9 + r) * 64 + threadIdx.x, wf32);
        blsum[(l * 4 + dt) * 64 + threadIdx.x] = s;
    }
}

// ---------- consolidated CSR build ----------
struct EdgeArgs {
    const int* ei[9];
    long eoff[10];
    int cntoff[9];
    int srcbase[9];
};

// count + emit per-edge rank (coalesced)
__global__ void count_all(EdgeArgs ea, const unsigned int* __restrict__ flags,
                          int* __restrict__ cnt, int* __restrict__ rank) {
    long e = (long)blockIdx.x * 256 + threadIdx.x;
    if (e >= ea.eoff[9]) return;
    int r = 0;
    while (r < 8 && e >= ea.eoff[r + 1]) ++r;
    long el = e - ea.eoff[r];
    long E = ea.eoff[r + 1] - ea.eoff[r];
    bool is64 = (flags[0] == 0u);
    const int* ei = ea.ei[r];
    int dst = is64 ? ei[2 * E + 2 * el] : ei[E + el];
    rank[e] = atomicAdd(&cnt[ea.cntoff[r] + dst], 1);
}

// atomic-free fill: pos = row_ptr[dst] + rank[e]
__global__ void fill_all(EdgeArgs ea, const unsigned int* __restrict__ flags,
                         const int* __restrict__ row_ptr, const int* __restrict__ rank,
                         int* __restrict__ edge_src) {
    long e = (long)blockIdx.x * 256 + threadIdx.x;
    if (e >= ea.eoff[9]) return;
    int r = 0;
    while (r < 8 && e >= ea.eoff[r + 1]) ++r;
    long el = e - ea.eoff[r];
    long E = ea.eoff[r + 1] - ea.eoff[r];
    bool is64 = (flags[0] == 0u);
    const int* ei = ea.ei[r];
    int src, dst;
    if (is64) { src = ei[2 * el]; dst = ei[2 * E + 2 * el]; }
    else      { src = ei[el];     dst = ei[E + el]; }
    int pos = row_ptr[ea.cntoff[r] + dst] + rank[e];
    edge_src[pos] = ea.srcbase[r] + src;
}

__global__ void scan_bsum(const int* __restrict__ cnt, int n, int* __restrict__ bsums) {
    __shared__ int red[256];
    int i = blockIdx.x * 256 + threadIdx.x;
    red[threadIdx.x] = (i < n) ? cnt[i] : 0;
    __syncthreads();
    for (int s = 128; s; s >>= 1) {
        if (threadIdx.x < s) red[threadIdx.x] += red[threadIdx.x + s];
        __syncthreads();
    }
    if (threadIdx.x == 0) bsums[blockIdx.x] = red[0];
}

__global__ void scan_excl_single(int* __restrict__ data, int n) {
    __shared__ int buf[1024];
    __shared__ int carry_s;
    if (threadIdx.x == 0) carry_s = 0;
    __syncthreads();
    for (int base = 0; base < n; base += 1024) {
        int i = base + threadIdx.x;
        int v = (i < n) ? data[i] : 0;
        buf[threadIdx.x] = v;
        __syncthreads();
        for (int off = 1; off < 1024; off <<= 1) {
            int tv = (threadIdx.x >= off) ? buf[threadIdx.x - off] : 0;
            __syncthreads();
            buf[threadIdx.x] += tv;
            __syncthreads();
        }
        int incl = buf[threadIdx.x];
        int carry = carry_s;
        if (i < n) data[i] = carry + incl - v;
        __syncthreads();
        if (threadIdx.x == 1023) carry_s = carry + buf[1023];
        __syncthreads();
    }
}

__global__ void scan_rowptr(const int* __restrict__ cnt, const int* __restrict__ bsums,
                            int n, int* __restrict__ row_ptr) {
    __shared__ int buf[256];
    int i = blockIdx.x * 256 + threadIdx.x;
    int v = (i < n) ? cnt[i] : 0;
    buf[threadIdx.x] = v;
    __syncthreads();
    for (int off = 1; off < 256; off <<= 1) {
        int tv = (threadIdx.x >= off) ? buf[threadIdx.x - off] : 0;
        __syncthreads();
        buf[threadIdx.x] += tv;
        __syncthreads();
    }
    int excl = buf[threadIdx.x] - v + bsums[blockIdx.x];
    if (i < n) row_ptr[i] = excl;
    if (i == n - 1) row_ptr[n] = excl + v;
}

// ---------- fused layer: gather-mean into LDS + MFMA update, ping-pong x ----------
// Per block: one 64-row dst tile. For each relation p<R: gather mean rows into
// XOR-swizzled LDS, then MFMA A from LDS. Self pass reads xin directly. Writes
// relu(acc+bias) to xout. agg is never materialized.
struct FusedArgs {
    int cntOff[4][3];
    int wtSlot[4][4];
    long dstBase[4];
    int nDst[4];
    int Rdt[4];
    int blsumOff[4];
    int btBase[5];
};

__global__ __launch_bounds__(256) void fused_layer(
    const __hip_bfloat16* __restrict__ xin,
    __hip_bfloat16* __restrict__ xout,
    const int* __restrict__ edge_src,
    const int* __restrict__ row_ptr,
    const bf16_t* __restrict__ wt,
    const float* __restrict__ blsum,
    FusedArgs fa) {
    __shared__ unsigned lds[64 * 32];   // 64 rows x 128B, dword-swizzled

    int bt = blockIdx.x;
    int dt = 0;
    while (dt < 3 && bt >= fa.btBase[dt + 1]) ++dt;
    int R = fa.Rdt[dt];
    int t0 = bt - fa.btBase[dt];
    int nD = fa.nDst[dt];

    int tid = threadIdx.x;
    int gr = tid >> 2, gp = tid & 3;          // gather: row 0..63, 32B part 0..3
    bool rowValid = (t0 * 64 + gr < nD);
    int wv = tid >> 6, lane = tid & 63;
    int quad = lane >> 4, l16 = lane & 15;

    const uint4* xq = (const uint4*)xin;      // one x row = 8 uint4
    f32x4 acc[4] = {};

    for (int p = 0; p < R; ++p) {
        int rp0 = 0, rp1 = 0;
        if (rowValid) {
            int cr = fa.cntOff[dt][p] + t0 * 64 + gr;
            rp0 = row_ptr[cr]; rp1 = row_ptr[cr + 1];
        }
        float s[16];
        #pragma unroll
        for (int j = 0; j < 16; ++j) s[j] = 0.f;

        {   // static first-4-edges pipeline
            int idx4[4];
            #pragma unroll
            for (int j = 0; j < 4; ++j) {
                int ee = rp0 + j;
                idx4[j] = edge_src[(ee < rp1) ? ee : 0];
            }
            uint4 v0[4], v1[4];
            #pragma unroll
            for (int j = 0; j < 4; ++j) {
                bool ok = (rp0 + j < rp1);
                unsigned ofs = (unsigned)idx4[j] * 8u + (unsigned)gp * 2u;
                v0[j] = xq[ok ? ofs : 0u];
                v1[j] = xq[ok ? ofs + 1u : 0u];
            }
            #pragma unroll
            for (int j = 0; j < 4; ++j) {
                unsigned m = (rp0 + j < rp1) ? 0xFFFFFFFFu : 0u;
                acc8(s, v0[j], m);
                acc8(s + 8, v1[j], m);
            }
        }
        for (int e = rp0 + 4; e < rp1; e += 4) {   // leftover (deg>4 rows)
            int idx4[4];
            #pragma unroll
            for (int j = 0; j < 4; ++j) {
                int ee = e + j;
                idx4[j] = edge_src[(ee < rp1) ? ee : 0];
            }
            uint4 v0[4], v1[4];
            #pragma unroll
            for (int j = 0; j < 4; ++j) {
                bool ok = (e + j < rp1);
                unsigned ofs = (unsigned)idx4[j] * 8u + (unsigned)gp * 2u;
                v0[j] = xq[ok ? ofs : 0u];
                v1[j] = xq[ok ? ofs + 1u : 0u];
            }
            #pragma unroll
            for (int j = 0; j < 4; ++j) {
                unsigned m = (e + j < rp1) ? 0xFFFFFFFFu : 0u;
                acc8(s, v0[j], m);
                acc8(s + 8, v1[j], m);
            }
        }

        float inv = (rp1 > rp0) ? 1.0f / (float)(rp1 - rp0) : 0.f;
        unsigned base = (unsigned)gr * 32u;
        #pragma unroll
        for (int h = 0; h < 2; ++h) {
            int d = gp * 8 + h * 4;
            unsigned idx = base + (unsigned)(d ^ ((gr & 7) << 2));
            uint4 o;
            o.x = packbf(s[h * 8 + 0] * inv, s[h * 8 + 1] * inv);
            o.y = packbf(s[h * 8 + 2] * inv, s[h * 8 + 3] * inv);
            o.z = packbf(s[h * 8 + 4] * inv, s[h * 8 + 5] * inv);
            o.w = packbf(s[h * 8 + 6] * inv, s[h * 8 + 7] * inv);
            *(uint4*)&lds[idx] = o;
        }
        __syncthreads();

        const bf16_t* wb = wt + (long)fa.wtSlot[dt][p] * 4096;
        int ar = wv * 16 + l16;
        unsigned i0 = (unsigned)ar * 32u + (unsigned)((quad * 4) ^ ((ar & 7) << 2));
        unsigned i1 = (unsigned)ar * 32u + (unsigned)(((16 + quad * 4)) ^ ((ar & 7) << 2));
        bf16x8 a0 = *(const bf16x8*)&lds[i0];
        bf16x8 a1 = *(const bf16x8*)&lds[i1];
        #pragma unroll
        for (int nt = 0; nt < 4; ++nt) {
            bf16x8 b0 = *(const bf16x8*)(wb + (nt * 16 + l16) * 64 + quad * 8);
            bf16x8 b1 = *(const bf16x8*)(wb + (nt * 16 + l16) * 64 + 32 + quad * 8);
            acc[nt] = __builtin_amdgcn_mfma_f32_16x16x32_bf16(a0, b0, acc[nt], 0, 0, 0);
            acc[nt] = __builtin_amdgcn_mfma_f32_16x16x32_bf16(a1, b1, acc[nt], 0, 0, 0);
        }
        __syncthreads();
    }

    // self pass: A = xin rows of this tile (x buffers padded +64 rows for tails)
    {
        const bf16_t* wb = wt + (long)fa.wtSlot[dt][3] * 4096;
        const bf16_t* ab = (const bf16_t*)xin + (fa.dstBase[dt] + (long)t0 * 64 + wv * 16) * 64;
        bf16x8 a0 = *(const bf16x8*)(ab + l16 * 64 + quad * 8);
        bf16x8 a1 = *(const bf16x8*)(ab + l16 * 64 + 32 + quad * 8);
        #pragma unroll
        for (int nt = 0; nt < 4; ++nt) {
            bf16x8 b0 = *(const bf16x8*)(wb + (nt * 16 + l16) * 64 + quad * 8);
            bf16x8 b1 = *(const bf16x8*)(wb + (nt * 16 + l16) * 64 + 32 + quad * 8);
            acc[nt] = __builtin_amdgcn_mfma_f32_16x16x32_bf16(a0, b0, acc[nt], 0, 0, 0);
            acc[nt] = __builtin_amdgcn_mfma_f32_16x16x32_bf16(a1, b1, acc[nt], 0, 0, 0);
        }
    }

    const float* bs = blsum + fa.blsumOff[dt];
    #pragma unroll
    for (int nt = 0; nt < 4; ++nt) {
        int col = nt * 16 + l16;
        float bv = bs[col];
        #pragma unroll
        for (int reg = 0; reg < 4; ++reg) {
            long dd = (long)t0 * 64 + wv * 16 + quad * 4 + reg;
            if (dd < nD)
                xout[(fa.dstBase[dt] + dd) * 64 + col] =
                    __float2bfloat16(fmaxf(acc[nt][reg] + bv, 0.f));
        }
    }
}

// ---------- head: softplus(x@projW+projb) @ outW + outb ----------
__global__ __launch_bounds__(256) void head_k(
    const __hip_bfloat16* __restrict__ xc,
    const void* __restrict__ projW, const void* __restrict__ projb,
    const void* __restrict__ outW, const void* __restrict__ outb,
    void* __restrict__ out, const unsigned int* __restrict__ flags, int n) {
    __shared__ float PW[64 * 64];
    __shared__ float PB[64], OW[64];
    __shared__ float ROW[4][64];
    bool wf32 = flags[2] > 64;
    bool of32 = flags[1] > 64;
    int t = threadIdx.x;
    for (int i = t; i < 4096; i += 256) PW[i] = wload(projW, i, wf32);
    if (t < 64) { PB[t] = wload(projb, t, wf32); OW[t] = wload(outW, t, wf32); }
    int wid = t >> 6, lane = t & 63;
    int d = blockIdx.x * 4 + wid;
    ROW[wid][lane] = (d < n) ? __bfloat162float(xc[(long)d * H64 + lane]) : 0.f;
    __syncthreads();
    if (d < n) {
        float s = PB[lane];
        #pragma unroll 8
        for (int k = 0; k < 64; ++k) s += ROW[wid][k] * PW[k * 64 + lane];
        float sp = fmaxf(s, 0.f) + log1pf(expf(-fabsf(s)));
        float c = sp * OW[lane];
        #pragma unroll
        for (int off = 32; off; off >>= 1) c += __shfl_down(c, off, 64);
        if (lane == 0) {
            float rv = c + wload(outb, 0, wf32);
            if (of32) ((float*)out)[d] = rv;
            else ((__hip_bfloat16*)out)[d] = __float2bfloat16(rv);
        }
    }
}

extern "C" void kernel_launch(void* const* d_in, const int* in_sizes, int n_in,
                              void* d_out, int out_size, void* d_ws, size_t ws_size,
                              hipStream_t stream) {
    static const int rel_st[9] = {0, 0, 0, 1, 1, 2, 0, 1, 2};
    static const int rel_dt[9] = {0, 1, 2, 1, 2, 2, 3, 3, 3};
    static const int relsOf[4][3] = {{0, -1, -1}, {1, 3, -1}, {2, 4, 5}, {6, 7, 8}};
    static const int Rof[4] = {1, 2, 3, 3};

    long rows[4], rowoff[4], total = 0;
    for (int t = 0; t < 4; ++t) { rows[t] = in_sizes[t] / H64; rowoff[t] = total; total += rows[t]; }
    long NX = total * H64;
    long NXpad = (total + 64) * H64;           // +64 rows: tail-tile overread safety
    long Es[9], ET = 0;
    for (int r = 0; r < 9; ++r) { Es[r] = (long)in_sizes[11 + r] / 2; ET += Es[r]; }
    long cntoff[9], cntN = 0;
    for (int r = 0; r < 9; ++r) { cntoff[r] = cntN; cntN += rows[rel_dt[r]]; }
    long nb1 = (cntN + 255) / 256;

    unsigned int* flags = (unsigned int*)d_ws;
    char* wsbase = (char*)d_ws + 64;
    auto align16 = [](size_t v) { return (v + 15) & ~(size_t)15; };
    size_t off = 0;
    __hip_bfloat16* x0 = (__hip_bfloat16*)(wsbase + off);  off = align16(off + (size_t)NXpad * 2);
    __hip_bfloat16* x1 = (__hip_bfloat16*)(wsbase + off);  off = align16(off + (size_t)NXpad * 2);
    int* cnt_i = (int*)(wsbase + off);                     off = align16(off + (size_t)cntN * 4);
    int* row_ptr = (int*)(wsbase + off);                   off = align16(off + (size_t)(cntN + 1) * 4);
    int* rank = (int*)(wsbase + off);                      off = align16(off + (size_t)ET * 4);
    int* edge_src = (int*)(wsbase + off);                  off = align16(off + (size_t)ET * 4);
    int* bsums = (int*)(wsbase + off);                     off = align16(off + (size_t)nb1 * 4);
    bf16_t* wt = (bf16_t*)(wsbase + off);                  off = align16(off + (size_t)39 * 4096 * 2);
    float* blsum = (float*)(wsbase + off);                 off = align16(off + (size_t)12 * 64 * 4);

    // format detection
    hipMemsetAsync(d_ws, 0, 64, stream);
    int nwords = 16384;
    if (in_sizes[11] < nwords) nwords = in_sizes[11];
    detect_k<<<1, 256, 0, stream>>>((const unsigned int*)d_in[11], nwords,
                                    (const unsigned short*)d_in[0],
                                    (const unsigned short*)d_in[4], flags);

    // x inputs -> bf16 ws (single dispatch)
    ConvArgs ca;
    for (int t = 0; t < 4; ++t) { ca.src[t] = d_in[t]; ca.elemoff[t] = rowoff[t] * H64; }
    ca.elemoff[4] = NX;
    {
        int blocks = (int)((NX + 255) / 256); if (blocks > 8192) blocks = 8192;
        conv_in_all<<<blocks, 256, 0, stream>>>(ca, x0, flags);
    }

    // weight prep (transpose + pre-sum, bf16)
    prep_w<<<39, 256, 0, stream>>>(d_in[4], d_in[6], d_in[5], flags, wt, blsum);

    // CSR build (edge structure is layer-invariant)
    EdgeArgs ea;
    long ecum = 0;
    for (int r = 0; r < 9; ++r) {
        ea.ei[r] = (const int*)d_in[11 + r];
        ea.eoff[r] = ecum; ecum += Es[r];
        ea.cntoff[r] = (int)cntoff[r];
        ea.srcbase[r] = (int)rowoff[rel_st[r]];
    }
    ea.eoff[9] = ecum;

    hipMemsetAsync(cnt_i, 0, (size_t)cntN * 4, stream);
    count_all<<<(int)((ET + 255) / 256), 256, 0, stream>>>(ea, flags, cnt_i, rank);
    scan_bsum<<<(int)nb1, 256, 0, stream>>>(cnt_i, (int)cntN, bsums);
    scan_excl_single<<<1, 1024, 0, stream>>>(bsums, (int)nb1);
    scan_rowptr<<<(int)nb1, 256, 0, stream>>>(cnt_i, bsums, (int)cntN, row_ptr);
    fill_all<<<(int)((ET + 255) / 256), 256, 0, stream>>>(ea, flags, row_ptr, rank, edge_src);

    // fused-layer argument block (layer-invariant parts)
    FusedArgs fa;
    int bb = 0;
    for (int dt = 0; dt < 4; ++dt) {
        fa.nDst[dt] = (int)rows[dt];
        fa.Rdt[dt] = Rof[dt];
        fa.dstBase[dt] = rowoff[dt];
        fa.btBase[dt] = bb;
        bb += (int)((rows[dt] + 63) / 64);
        for (int p = 0; p < 3; ++p) {
            int rr = (p < Rof[dt]) ? relsOf[dt][p] : relsOf[dt][0];
            fa.cntOff[dt][p] = (int)cntoff[rr];
        }
    }
    fa.btBase[4] = bb;

    // layers: fused gather+update, ping-pong x
    for (int l = 0; l < 3; ++l) {
        for (int dt = 0; dt < 4; ++dt) {
            fa.blsumOff[dt] = (l * 4 + dt) * 64;
            for (int p = 0; p < 3; ++p) {
                int rr = (p < Rof[dt]) ? relsOf[dt][p] : relsOf[dt][0];
                fa.wtSlot[dt][p] = l * 13 + rr;
            }
            fa.wtSlot[dt][3] = l * 13 + 9 + dt;
        }
        const __hip_bfloat16* xin = (l & 1) ? x1 : x0;
        __hip_bfloat16* xo = (l & 1) ? x0 : x1;
        fused_layer<<<bb, 256, 0, stream>>>(xin, xo, edge_src, row_ptr, wt, blsum, fa);
    }

    // 3 layers -> final state in x1
    head_k<<<(int)((rows[3] + 3) / 4), 256, 0, stream>>>(
        x1 + rowoff[3] * H64, d_in[7], d_in[8], d_in[9], d_in[10], d_out, flags, (int)rows[3]);
}

// Round 5
// 849.710 us; speedup vs baseline: 1.1973x; 1.0393x over previous
//
#include <hip/hip_runtime.h>
#include <hip/hip_bf16.h>

#define H64 64

typedef __bf16 bf16_t;
typedef __bf16 bf16x8 __attribute__((ext_vector_type(8)));
typedef float f32x4 __attribute__((ext_vector_type(4)));

// ---------- helpers ----------
__device__ __forceinline__ float wload(const void* p, long i, bool f32) {
    return f32 ? ((const float*)p)[i]
               : __bfloat162float(((const __hip_bfloat16*)p)[i]);
}
__device__ __forceinline__ float blo(unsigned v) { return __uint_as_float(v << 16); }
__device__ __forceinline__ float bhi(unsigned v) { return __uint_as_float(v & 0xffff0000u); }
__device__ __forceinline__ unsigned packbf(float lo, float hi) {
    __hip_bfloat162 t;
    t.x = __float2bfloat16(lo);
    t.y = __float2bfloat16(hi);
    return *(unsigned*)&t;
}
__device__ __forceinline__ void acc8(float* s, uint4 v, unsigned m) {
    s[0] += blo(v.x & m); s[1] += bhi(v.x & m);
    s[2] += blo(v.y & m); s[3] += bhi(v.y & m);
    s[4] += blo(v.z & m); s[5] += bhi(v.z & m);
    s[6] += blo(v.w & m); s[7] += bhi(v.w & m);
}

// ---------- runtime format detection ----------
// flags[0] != 0 -> edge indices int32 (odd words nonzero); ==0 -> int64
// flags[1] > 64 -> x tensors f32; else bf16.  flags[2] > 64 -> weights f32.
__global__ void detect_k(const unsigned int* __restrict__ eiw, int nwords,
                         const unsigned short* __restrict__ xw,
                         const unsigned short* __restrict__ ww,
                         unsigned int* __restrict__ flags) {
    int t = threadIdx.x;
    unsigned int acc = 0;
    for (int i = 1 + 2 * t; i < nwords; i += 512) acc |= eiw[i];
    if (acc) atomicOr(&flags[0], acc);
    unsigned int cx = 0, cw = 0;
    for (int i = t; i < 8192; i += 256) {
        unsigned short w = xw[i];
        unsigned int e = (w >> 7) & 0xFF;
        if ((w & 0x7FFF) && (e == 0xFF || e < 0x40)) cx++;
        w = ww[i];
        e = (w >> 7) & 0xFF;
        if ((w & 0x7FFF) && (e == 0xFF || e < 0x40)) cw++;
    }
    if (cx) atomicAdd(&flags[1], cx);
    if (cw) atomicAdd(&flags[2], cw);
}

// ---------- convert all x inputs -> bf16 ws storage (single dispatch) ----------
struct ConvArgs {
    const void* src[4];
    long elemoff[5];   // element offsets (rows*64) per type, cumulative
};
__global__ void conv_in_all(ConvArgs ca, __hip_bfloat16* __restrict__ dst,
                            const unsigned int* __restrict__ flags) {
    bool xf32 = flags[1] > 64;
    long n = ca.elemoff[4];
    long i = (long)blockIdx.x * blockDim.x + threadIdx.x;
    long stride = (long)gridDim.x * blockDim.x;
    for (; i < n; i += stride) {
        int t = (i >= ca.elemoff[2]) ? (i >= ca.elemoff[3] ? 3 : 2)
                                     : (i >= ca.elemoff[1] ? 1 : 0);
        long j = i - ca.elemoff[t];
        float v = xf32 ? ((const float*)ca.src[t])[j]
                       : __bfloat162float(((const __hip_bfloat16*)ca.src[t])[j]);
        dst[i] = __float2bfloat16(v);
    }
}

// ---------- weight prep: bf16, transposed WT[n][k]; Wr pre-summed per (l,dt) ----------
// blockIdx.x = l*13 + p.  p<9: WT of Wl[l,p].  p in 9..12: dt=p-9, WT of sum(Wr) + blsum.
__global__ void prep_w(const void* __restrict__ Wl, const void* __restrict__ Wr,
                       const void* __restrict__ bl, const unsigned int* __restrict__ flags,
                       bf16_t* __restrict__ wt, float* __restrict__ blsum) {
    const int rel_dt[9] = {0, 1, 2, 1, 2, 2, 3, 3, 3};
    bool wf32 = flags[2] > 64;
    int l = blockIdx.x / 13, p = blockIdx.x % 13;
    bf16_t* dst = wt + (long)blockIdx.x * 4096;
    for (int i = threadIdx.x; i < 4096; i += 256) {
        int n = i >> 6, k = i & 63;
        float v;
        if (p < 9) {
            v = wload(Wl, (long)(l * 9 + p) * 4096 + k * 64 + n, wf32);
        } else {
            int dt = p - 9;
            v = 0.f;
            for (int r = 0; r < 9; ++r)
                if (rel_dt[r] == dt) v += wload(Wr, (long)(l * 9 + r) * 4096 + k * 64 + n, wf32);
        }
        __hip_bfloat16 h = __float2bfloat16(v);
        dst[i] = *(bf16_t*)&h;
    }
    if (p >= 9 && threadIdx.x < 64) {
        int dt = p - 9;
        float s = 0.f;
        for (int r = 0; r < 9; ++r)
            if (rel_dt[r] == dt) s += wload(bl, (long)(l * 9 + r) * 64 + threadIdx.x, wf32);
        blsum[(l * 4 + dt) * 64 + threadIdx.x] = s;
    }
}

// ---------- consolidated CSR build ----------
struct EdgeArgs {
    const int* ei[9];
    long eoff[10];
    int cntoff[9];
    int srcbase[9];
};

// count + emit per-edge rank (coalesced)
__global__ void count_all(EdgeArgs ea, const unsigned int* __restrict__ flags,
                          int* __restrict__ cnt, int* __restrict__ rank) {
    long e = (long)blockIdx.x * 256 + threadIdx.x;
    if (e >= ea.eoff[9]) return;
    int r = 0;
    while (r < 8 && e >= ea.eoff[r + 1]) ++r;
    long el = e - ea.eoff[r];
    long E = ea.eoff[r + 1] - ea.eoff[r];
    bool is64 = (flags[0] == 0u);
    const int* ei = ea.ei[r];
    int dst = is64 ? ei[2 * E + 2 * el] : ei[E + el];
    rank[e] = atomicAdd(&cnt[ea.cntoff[r] + dst], 1);
}

// atomic-free fill: pos = row_ptr[dst] + rank[e]
__global__ void fill_all(EdgeArgs ea, const unsigned int* __restrict__ flags,
                         const int* __restrict__ row_ptr, const int* __restrict__ rank,
                         int* __restrict__ edge_src) {
    long e = (long)blockIdx.x * 256 + threadIdx.x;
    if (e >= ea.eoff[9]) return;
    int r = 0;
    while (r < 8 && e >= ea.eoff[r + 1]) ++r;
    long el = e - ea.eoff[r];
    long E = ea.eoff[r + 1] - ea.eoff[r];
    bool is64 = (flags[0] == 0u);
    const int* ei = ea.ei[r];
    int src, dst;
    if (is64) { src = ei[2 * el]; dst = ei[2 * E + 2 * el]; }
    else      { src = ei[el];     dst = ei[E + el]; }
    int pos = row_ptr[ea.cntoff[r] + dst] + rank[e];
    edge_src[pos] = ea.srcbase[r] + src;
}

__global__ void scan_bsum(const int* __restrict__ cnt, int n, int* __restrict__ bsums) {
    __shared__ int red[256];
    int i = blockIdx.x * 256 + threadIdx.x;
    red[threadIdx.x] = (i < n) ? cnt[i] : 0;
    __syncthreads();
    for (int s = 128; s; s >>= 1) {
        if (threadIdx.x < s) red[threadIdx.x] += red[threadIdx.x + s];
        __syncthreads();
    }
    if (threadIdx.x == 0) bsums[blockIdx.x] = red[0];
}

__global__ void scan_excl_single(int* __restrict__ data, int n) {
    __shared__ int buf[1024];
    __shared__ int carry_s;
    if (threadIdx.x == 0) carry_s = 0;
    __syncthreads();
    for (int base = 0; base < n; base += 1024) {
        int i = base + threadIdx.x;
        int v = (i < n) ? data[i] : 0;
        buf[threadIdx.x] = v;
        __syncthreads();
        for (int off = 1; off < 1024; off <<= 1) {
            int tv = (threadIdx.x >= off) ? buf[threadIdx.x - off] : 0;
            __syncthreads();
            buf[threadIdx.x] += tv;
            __syncthreads();
        }
        int incl = buf[threadIdx.x];
        int carry = carry_s;
        if (i < n) data[i] = carry + incl - v;
        __syncthreads();
        if (threadIdx.x == 1023) carry_s = carry + buf[1023];
        __syncthreads();
    }
}

__global__ void scan_rowptr(const int* __restrict__ cnt, const int* __restrict__ bsums,
                            int n, int* __restrict__ row_ptr) {
    __shared__ int buf[256];
    int i = blockIdx.x * 256 + threadIdx.x;
    int v = (i < n) ? cnt[i] : 0;
    buf[threadIdx.x] = v;
    __syncthreads();
    for (int off = 1; off < 256; off <<= 1) {
        int tv = (threadIdx.x >= off) ? buf[threadIdx.x - off] : 0;
        __syncthreads();
        buf[threadIdx.x] += tv;
        __syncthreads();
    }
    int excl = buf[threadIdx.x] - v + bsums[blockIdx.x];
    if (i < n) row_ptr[i] = excl;
    if (i == n - 1) row_ptr[n] = excl + v;
}

// ---------- fused layer v2: per-WAVE 16-row tiles, barrier-free ----------
// Each wave gathers R relation-means into its private LDS region (depth-4
// static pipeline, 4 threads/row x 32B), then lgkmcnt-waits and runs the
// MFMA update + epilogue. No __syncthreads -> waves free-run like the
// standalone gather (which sustained 3.2 TB/s). agg never materialized.
struct FusedArgs {
    int cntOff[4][3];
    int wtSlot[4][4];
    long dstBase[4];
    int nDst[4];
    int Rdt[4];
    int blsumOff[4];
    int btBase[5];   // in 16-row-tile units, heavy-first order
    int dtOf[4];
    int totalT16;
};

__device__ __forceinline__ void gather_pass(
    unsigned* __restrict__ L,          // this pass's 16x32-dword region
    const uint4* __restrict__ xq,
    const int* __restrict__ edge_src,
    const int* __restrict__ row_ptr,
    int cr, bool valid, int gr, int gp) {
    int rp0 = 0, rp1 = 0;
    if (valid) { rp0 = row_ptr[cr]; rp1 = row_ptr[cr + 1]; }
    float s[16];
    #pragma unroll
    for (int j = 0; j < 16; ++j) s[j] = 0.f;
    {   // static first-4-edges pipeline
        int idx4[4];
        #pragma unroll
        for (int j = 0; j < 4; ++j) {
            int ee = rp0 + j;
            idx4[j] = edge_src[(ee < rp1) ? ee : 0];
        }
        uint4 v0[4], v1[4];
        #pragma unroll
        for (int j = 0; j < 4; ++j) {
            bool ok = (rp0 + j < rp1);
            unsigned ofs = (unsigned)idx4[j] * 8u + (unsigned)gp * 2u;
            v0[j] = xq[ok ? ofs : 0u];
            v1[j] = xq[ok ? ofs + 1u : 0u];
        }
        #pragma unroll
        for (int j = 0; j < 4; ++j) {
            unsigned m = (rp0 + j < rp1) ? 0xFFFFFFFFu : 0u;
            acc8(s, v0[j], m);
            acc8(s + 8, v1[j], m);
        }
    }
    for (int e = rp0 + 4; e < rp1; e += 4) {   // leftover (deg>4 rows)
        int idx4[4];
        #pragma unroll
        for (int j = 0; j < 4; ++j) {
            int ee = e + j;
            idx4[j] = edge_src[(ee < rp1) ? ee : 0];
        }
        uint4 v0[4], v1[4];
        #pragma unroll
        for (int j = 0; j < 4; ++j) {
            bool ok = (e + j < rp1);
            unsigned ofs = (unsigned)idx4[j] * 8u + (unsigned)gp * 2u;
            v0[j] = xq[ok ? ofs : 0u];
            v1[j] = xq[ok ? ofs + 1u : 0u];
        }
        #pragma unroll
        for (int j = 0; j < 4; ++j) {
            unsigned m = (e + j < rp1) ? 0xFFFFFFFFu : 0u;
            acc8(s, v0[j], m);
            acc8(s + 8, v1[j], m);
        }
    }
    float inv = (rp1 > rp0) ? 1.0f / (float)(rp1 - rp0) : 0.f;
    unsigned base = (unsigned)gr * 32u;
    #pragma unroll
    for (int h = 0; h < 2; ++h) {
        int d = gp * 8 + h * 4;
        unsigned idxw = base + (unsigned)(d ^ ((gr & 7) << 2));
        uint4 o;
        o.x = packbf(s[h * 8 + 0] * inv, s[h * 8 + 1] * inv);
        o.y = packbf(s[h * 8 + 2] * inv, s[h * 8 + 3] * inv);
        o.z = packbf(s[h * 8 + 4] * inv, s[h * 8 + 5] * inv);
        o.w = packbf(s[h * 8 + 6] * inv, s[h * 8 + 7] * inv);
        *(uint4*)&L[idxw] = o;
    }
}

__global__ __launch_bounds__(256) void fused_layer(
    const __hip_bfloat16* __restrict__ xin,
    __hip_bfloat16* __restrict__ xout,
    const int* __restrict__ edge_src,
    const int* __restrict__ row_ptr,
    const bf16_t* __restrict__ wt,
    const float* __restrict__ blsum,
    FusedArgs fa) {
    __shared__ unsigned lds[4][3 * 512];   // per wave: 3 regions x 16 rows x 128B

    int wv = threadIdx.x >> 6;
    int g = blockIdx.x * 4 + wv;
    if (g >= fa.totalT16) return;
    int slot = 0;
    while (slot < 3 && g >= fa.btBase[slot + 1]) ++slot;
    int dt = fa.dtOf[slot];
    int t0 = g - fa.btBase[slot];
    int nD = fa.nDst[dt];
    int R = fa.Rdt[dt];

    int lane = threadIdx.x & 63;
    int gr = lane >> 2, gp = lane & 3;     // gather: row 0..15, 32B part 0..3
    int row = t0 * 16 + gr;
    bool valid = (row < nD);
    int quad = lane >> 4, l16 = lane & 15; // MFMA roles

    const uint4* xq = (const uint4*)xin;
    unsigned* L = lds[wv];

    for (int p = 0; p < R; ++p)
        gather_pass(L + p * 512, xq, edge_src, row_ptr,
                    fa.cntOff[dt][p] + row, valid, gr, gp);

    // same-wave ds_write -> ds_read ordering; no cross-wave dependency exists
    asm volatile("s_waitcnt lgkmcnt(0)" ::: "memory");

    f32x4 acc[4] = {};
    for (int p = 0; p < R; ++p) {
        const bf16_t* wb = wt + (long)fa.wtSlot[dt][p] * 4096;
        unsigned sw = (unsigned)((l16 & 7) << 2);
        unsigned i0 = (unsigned)(p * 512) + (unsigned)l16 * 32u + ((unsigned)(quad * 4) ^ sw);
        unsigned i1 = (unsigned)(p * 512) + (unsigned)l16 * 32u + ((unsigned)(16 + quad * 4) ^ sw);
        bf16x8 a0 = *(const bf16x8*)&L[i0];
        bf16x8 a1 = *(const bf16x8*)&L[i1];
        #pragma unroll
        for (int nt = 0; nt < 4; ++nt) {
            bf16x8 b0 = *(const bf16x8*)(wb + (nt * 16 + l16) * 64 + quad * 8);
            bf16x8 b1 = *(const bf16x8*)(wb + (nt * 16 + l16) * 64 + 32 + quad * 8);
            acc[nt] = __builtin_amdgcn_mfma_f32_16x16x32_bf16(a0, b0, acc[nt], 0, 0, 0);
            acc[nt] = __builtin_amdgcn_mfma_f32_16x16x32_bf16(a1, b1, acc[nt], 0, 0, 0);
        }
    }

    // self pass: A = xin rows of this tile (x buffers padded +64 rows for tails)
    {
        const bf16_t* wb = wt + (long)fa.wtSlot[dt][3] * 4096;
        const bf16_t* ab = (const bf16_t*)xin + (fa.dstBase[dt] + (long)t0 * 16) * 64;
        bf16x8 a0 = *(const bf16x8*)(ab + l16 * 64 + quad * 8);
        bf16x8 a1 = *(const bf16x8*)(ab + l16 * 64 + 32 + quad * 8);
        #pragma unroll
        for (int nt = 0; nt < 4; ++nt) {
            bf16x8 b0 = *(const bf16x8*)(wb + (nt * 16 + l16) * 64 + quad * 8);
            bf16x8 b1 = *(const bf16x8*)(wb + (nt * 16 + l16) * 64 + 32 + quad * 8);
            acc[nt] = __builtin_amdgcn_mfma_f32_16x16x32_bf16(a0, b0, acc[nt], 0, 0, 0);
            acc[nt] = __builtin_amdgcn_mfma_f32_16x16x32_bf16(a1, b1, acc[nt], 0, 0, 0);
        }
    }

    const float* bs = blsum + fa.blsumOff[dt];
    #pragma unroll
    for (int nt = 0; nt < 4; ++nt) {
        int col = nt * 16 + l16;
        float bv = bs[col];
        #pragma unroll
        for (int reg = 0; reg < 4; ++reg) {
            long dd = (long)t0 * 16 + quad * 4 + reg;
            if (dd < nD)
                xout[(fa.dstBase[dt] + dd) * 64 + col] =
                    __float2bfloat16(fmaxf(acc[nt][reg] + bv, 0.f));
        }
    }
}

// ---------- head: softplus(x@projW+projb) @ outW + outb ----------
__global__ __launch_bounds__(256) void head_k(
    const __hip_bfloat16* __restrict__ xc,
    const void* __restrict__ projW, const void* __restrict__ projb,
    const void* __restrict__ outW, const void* __restrict__ outb,
    void* __restrict__ out, const unsigned int* __restrict__ flags, int n) {
    __shared__ float PW[64 * 64];
    __shared__ float PB[64], OW[64];
    __shared__ float ROW[4][64];
    bool wf32 = flags[2] > 64;
    bool of32 = flags[1] > 64;
    int t = threadIdx.x;
    for (int i = t; i < 4096; i += 256) PW[i] = wload(projW, i, wf32);
    if (t < 64) { PB[t] = wload(projb, t, wf32); OW[t] = wload(outW, t, wf32); }
    int wid = t >> 6, lane = t & 63;
    int d = blockIdx.x * 4 + wid;
    ROW[wid][lane] = (d < n) ? __bfloat162float(xc[(long)d * H64 + lane]) : 0.f;
    __syncthreads();
    if (d < n) {
        float s = PB[lane];
        #pragma unroll 8
        for (int k = 0; k < 64; ++k) s += ROW[wid][k] * PW[k * 64 + lane];
        float sp = fmaxf(s, 0.f) + log1pf(expf(-fabsf(s)));
        float c = sp * OW[lane];
        #pragma unroll
        for (int off = 32; off; off >>= 1) c += __shfl_down(c, off, 64);
        if (lane == 0) {
            float rv = c + wload(outb, 0, wf32);
            if (of32) ((float*)out)[d] = rv;
            else ((__hip_bfloat16*)out)[d] = __float2bfloat16(rv);
        }
    }
}

extern "C" void kernel_launch(void* const* d_in, const int* in_sizes, int n_in,
                              void* d_out, int out_size, void* d_ws, size_t ws_size,
                              hipStream_t stream) {
    static const int rel_st[9] = {0, 0, 0, 1, 1, 2, 0, 1, 2};
    static const int rel_dt[9] = {0, 1, 2, 1, 2, 2, 3, 3, 3};
    static const int relsOf[4][3] = {{0, -1, -1}, {1, 3, -1}, {2, 4, 5}, {6, 7, 8}};
    static const int Rof[4] = {1, 2, 3, 3};
    static const int order[4] = {3, 0, 2, 1};   // heavy tiles first (cell, atom, motif, bond)

    long rows[4], rowoff[4], total = 0;
    for (int t = 0; t < 4; ++t) { rows[t] = in_sizes[t] / H64; rowoff[t] = total; total += rows[t]; }
    long NX = total * H64;
    long NXpad = (total + 64) * H64;           // +64 rows: tail-tile overread safety
    long Es[9], ET = 0;
    for (int r = 0; r < 9; ++r) { Es[r] = (long)in_sizes[11 + r] / 2; ET += Es[r]; }
    long cntoff[9], cntN = 0;
    for (int r = 0; r < 9; ++r) { cntoff[r] = cntN; cntN += rows[rel_dt[r]]; }
    long nb1 = (cntN + 255) / 256;

    unsigned int* flags = (unsigned int*)d_ws;
    char* wsbase = (char*)d_ws + 64;
    auto align16 = [](size_t v) { return (v + 15) & ~(size_t)15; };
    size_t off = 0;
    __hip_bfloat16* x0 = (__hip_bfloat16*)(wsbase + off);  off = align16(off + (size_t)NXpad * 2);
    __hip_bfloat16* x1 = (__hip_bfloat16*)(wsbase + off);  off = align16(off + (size_t)NXpad * 2);
    int* cnt_i = (int*)(wsbase + off);                     off = align16(off + (size_t)cntN * 4);
    int* row_ptr = (int*)(wsbase + off);                   off = align16(off + (size_t)(cntN + 1) * 4);
    int* rank = (int*)(wsbase + off);                      off = align16(off + (size_t)ET * 4);
    int* edge_src = (int*)(wsbase + off);                  off = align16(off + (size_t)ET * 4);
    int* bsums = (int*)(wsbase + off);                     off = align16(off + (size_t)nb1 * 4);
    bf16_t* wt = (bf16_t*)(wsbase + off);                  off = align16(off + (size_t)39 * 4096 * 2);
    float* blsum = (float*)(wsbase + off);                 off = align16(off + (size_t)12 * 64 * 4);

    // format detection
    hipMemsetAsync(d_ws, 0, 64, stream);
    int nwords = 16384;
    if (in_sizes[11] < nwords) nwords = in_sizes[11];
    detect_k<<<1, 256, 0, stream>>>((const unsigned int*)d_in[11], nwords,
                                    (const unsigned short*)d_in[0],
                                    (const unsigned short*)d_in[4], flags);

    // x inputs -> bf16 ws (single dispatch)
    ConvArgs ca;
    for (int t = 0; t < 4; ++t) { ca.src[t] = d_in[t]; ca.elemoff[t] = rowoff[t] * H64; }
    ca.elemoff[4] = NX;
    {
        int blocks = (int)((NX + 255) / 256); if (blocks > 8192) blocks = 8192;
        conv_in_all<<<blocks, 256, 0, stream>>>(ca, x0, flags);
    }

    // weight prep (transpose + pre-sum, bf16)
    prep_w<<<39, 256, 0, stream>>>(d_in[4], d_in[6], d_in[5], flags, wt, blsum);

    // CSR build (edge structure is layer-invariant)
    EdgeArgs ea;
    long ecum = 0;
    for (int r = 0; r < 9; ++r) {
        ea.ei[r] = (const int*)d_in[11 + r];
        ea.eoff[r] = ecum; ecum += Es[r];
        ea.cntoff[r] = (int)cntoff[r];
        ea.srcbase[r] = (int)rowoff[rel_st[r]];
    }
    ea.eoff[9] = ecum;

    hipMemsetAsync(cnt_i, 0, (size_t)cntN * 4, stream);
    count_all<<<(int)((ET + 255) / 256), 256, 0, stream>>>(ea, flags, cnt_i, rank);
    scan_bsum<<<(int)nb1, 256, 0, stream>>>(cnt_i, (int)cntN, bsums);
    scan_excl_single<<<1, 1024, 0, stream>>>(bsums, (int)nb1);
    scan_rowptr<<<(int)nb1, 256, 0, stream>>>(cnt_i, bsums, (int)cntN, row_ptr);
    fill_all<<<(int)((ET + 255) / 256), 256, 0, stream>>>(ea, flags, row_ptr, rank, edge_src);

    // fused-layer argument block (layer-invariant parts), 16-row tiles
    FusedArgs fa;
    int bb = 0;
    for (int s = 0; s < 4; ++s) {
        int dt = order[s];
        fa.dtOf[s] = dt;
        fa.btBase[s] = bb;
        bb += (int)((rows[dt] + 15) / 16);
    }
    fa.btBase[4] = bb;
    fa.totalT16 = bb;
    for (int dt = 0; dt < 4; ++dt) {
        fa.nDst[dt] = (int)rows[dt];
        fa.Rdt[dt] = Rof[dt];
        fa.dstBase[dt] = rowoff[dt];
        for (int p = 0; p < 3; ++p) {
            int rr = (p < Rof[dt]) ? relsOf[dt][p] : relsOf[dt][0];
            fa.cntOff[dt][p] = (int)cntoff[rr];
        }
    }

    // layers: fused gather+update, ping-pong x
    for (int l = 0; l < 3; ++l) {
        for (int dt = 0; dt < 4; ++dt) {
            fa.blsumOff[dt] = (l * 4 + dt) * 64;
            for (int p = 0; p < 3; ++p) {
                int rr = (p < Rof[dt]) ? relsOf[dt][p] : relsOf[dt][0];
                fa.wtSlot[dt][p] = l * 13 + rr;
            }
            fa.wtSlot[dt][3] = l * 13 + 9 + dt;
        }
        const __hip_bfloat16* xin = (l & 1) ? x1 : x0;
        __hip_bfloat16* xo = (l & 1) ? x0 : x1;
        fused_layer<<<(bb + 3) / 4, 256, 0, stream>>>(xin, xo, edge_src, row_ptr, wt, blsum, fa);
    }

    // 3 layers -> final state in x1
    head_k<<<(int)((rows[3] + 3) / 4), 256, 0, stream>>>(
        x1 + rowoff[3] * H64, d_in[7], d_in[8], d_in[9], d_in[10], d_out, flags, (int)rows[3]);
}

// Round 7
// 839.297 us; speedup vs baseline: 1.2121x; 1.0124x over previous
//
#include <hip/hip_runtime.h>
#include <hip/hip_bf16.h>

#define H64 64

typedef __bf16 bf16_t;
typedef __bf16 bf16x8 __attribute__((ext_vector_type(8)));
typedef float f32x4 __attribute__((ext_vector_type(4)));

// ---------- helpers ----------
__device__ __forceinline__ float wload(const void* p, long i, bool f32) {
    return f32 ? ((const float*)p)[i]
               : __bfloat162float(((const __hip_bfloat16*)p)[i]);
}
__device__ __forceinline__ float blo(unsigned v) { return __uint_as_float(v << 16); }
__device__ __forceinline__ float bhi(unsigned v) { return __uint_as_float(v & 0xffff0000u); }
__device__ __forceinline__ unsigned packbf(float lo, float hi) {
    __hip_bfloat162 t;
    t.x = __float2bfloat16(lo);
    t.y = __float2bfloat16(hi);
    return *(unsigned*)&t;
}
__device__ __forceinline__ void acc8(float* s, uint4 v, unsigned m) {
    s[0] += blo(v.x & m); s[1] += bhi(v.x & m);
    s[2] += blo(v.y & m); s[3] += bhi(v.y & m);
    s[4] += blo(v.z & m); s[5] += bhi(v.z & m);
    s[6] += blo(v.w & m); s[7] += bhi(v.w & m);
}

// ---------- runtime format detection ----------
// flags[0] != 0 -> edge indices int32 (odd words nonzero); ==0 -> int64
// flags[1] > 64 -> x tensors f32; else bf16.  flags[2] > 64 -> weights f32.
__global__ void detect_k(const unsigned int* __restrict__ eiw, int nwords,
                         const unsigned short* __restrict__ xw,
                         const unsigned short* __restrict__ ww,
                         unsigned int* __restrict__ flags) {
    int t = threadIdx.x;
    unsigned int acc = 0;
    for (int i = 1 + 2 * t; i < nwords; i += 512) acc |= eiw[i];
    if (acc) atomicOr(&flags[0], acc);
    unsigned int cx = 0, cw = 0;
    for (int i = t; i < 8192; i += 256) {
        unsigned short w = xw[i];
        unsigned int e = (w >> 7) & 0xFF;
        if ((w & 0x7FFF) && (e == 0xFF || e < 0x40)) cx++;
        w = ww[i];
        e = (w >> 7) & 0xFF;
        if ((w & 0x7FFF) && (e == 0xFF || e < 0x40)) cw++;
    }
    if (cx) atomicAdd(&flags[1], cx);
    if (cw) atomicAdd(&flags[2], cw);
}

// ---------- convert all x inputs -> bf16 ws storage (single dispatch) ----------
struct ConvArgs {
    const void* src[4];
    long elemoff[5];   // element offsets (rows*64) per type, cumulative
};
__global__ void conv_in_all(ConvArgs ca, __hip_bfloat16* __restrict__ dst,
                            const unsigned int* __restrict__ flags) {
    bool xf32 = flags[1] > 64;
    long n = ca.elemoff[4];
    long i = (long)blockIdx.x * blockDim.x + threadIdx.x;
    long stride = (long)gridDim.x * blockDim.x;
    for (; i < n; i += stride) {
        int t = (i >= ca.elemoff[2]) ? (i >= ca.elemoff[3] ? 3 : 2)
                                     : (i >= ca.elemoff[1] ? 1 : 0);
        long j = i - ca.elemoff[t];
        float v = xf32 ? ((const float*)ca.src[t])[j]
                       : __bfloat162float(((const __hip_bfloat16*)ca.src[t])[j]);
        dst[i] = __float2bfloat16(v);
    }
}

// ---------- weight prep: bf16, transposed WT[n][k]; Wr pre-summed per (l,dt) ----------
// blockIdx.x = l*13 + p.  p<9: WT of Wl[l,p].  p in 9..12: dt=p-9, WT of sum(Wr) + blsum.
__global__ void prep_w(const void* __restrict__ Wl, const void* __restrict__ Wr,
                       const void* __restrict__ bl, const unsigned int* __restrict__ flags,
                       bf16_t* __restrict__ wt, float* __restrict__ blsum) {
    const int rel_dt[9] = {0, 1, 2, 1, 2, 2, 3, 3, 3};
    bool wf32 = flags[2] > 64;
    int l = blockIdx.x / 13, p = blockIdx.x % 13;
    bf16_t* dst = wt + (long)blockIdx.x * 4096;
    for (int i = threadIdx.x; i < 4096; i += 256) {
        int n = i >> 6, k = i & 63;
        float v;
        if (p < 9) {
            v = wload(Wl, (long)(l * 9 + p) * 4096 + k * 64 + n, wf32);
        } else {
            int dt = p - 9;
            v = 0.f;
            for (int r = 0; r < 9; ++r)
                if (rel_dt[r] == dt) v += wload(Wr, (long)(l * 9 + r) * 4096 + k * 64 + n, wf32);
        }
        __hip_bfloat16 h = __float2bfloat16(v);
        dst[i] = *(bf16_t*)&h;
    }
    if (p >= 9 && threadIdx.x < 64) {
        int dt = p - 9;
        float s = 0.f;
        for (int r = 0; r < 9; ++r)
            if (rel_dt[r] == dt) s += wload(bl, (long)(l * 9 + r) * 64 + threadIdx.x, wf32);
        blsum[(l * 4 + dt) * 64 + threadIdx.x] = s;
    }
}

// ---------- consolidated CSR build ----------
struct EdgeArgs {
    const int* ei[9];
    long eoff[10];
    int cntoff[9];
    int srcbase[9];
};

// count + emit per-edge rank (coalesced)
__global__ void count_all(EdgeArgs ea, const unsigned int* __restrict__ flags,
                          int* __restrict__ cnt, int* __restrict__ rank) {
    long e = (long)blockIdx.x * 256 + threadIdx.x;
    if (e >= ea.eoff[9]) return;
    int r = 0;
    while (r < 8 && e >= ea.eoff[r + 1]) ++r;
    long el = e - ea.eoff[r];
    long E = ea.eoff[r + 1] - ea.eoff[r];
    bool is64 = (flags[0] == 0u);
    const int* ei = ea.ei[r];
    int dst = is64 ? ei[2 * E + 2 * el] : ei[E + el];
    rank[e] = atomicAdd(&cnt[ea.cntoff[r] + dst], 1);
}

// atomic-free fill: pos = row_ptr[dst] + rank[e]
__global__ void fill_all(EdgeArgs ea, const unsigned int* __restrict__ flags,
                         const int* __restrict__ row_ptr, const int* __restrict__ rank,
                         int* __restrict__ edge_src) {
    long e = (long)blockIdx.x * 256 + threadIdx.x;
    if (e >= ea.eoff[9]) return;
    int r = 0;
    while (r < 8 && e >= ea.eoff[r + 1]) ++r;
    long el = e - ea.eoff[r];
    long E = ea.eoff[r + 1] - ea.eoff[r];
    bool is64 = (flags[0] == 0u);
    const int* ei = ea.ei[r];
    int src, dst;
    if (is64) { src = ei[2 * el]; dst = ei[2 * E + 2 * el]; }
    else      { src = ei[el];     dst = ei[E + el]; }
    int pos = row_ptr[ea.cntoff[r] + dst] + rank[e];
    edge_src[pos] = ea.srcbase[r] + src;
}

__global__ void scan_bsum(const int* __restrict__ cnt, int n, int* __restrict__ bsums) {
    __shared__ int red[256];
    int i = blockIdx.x * 256 + threadIdx.x;
    red[threadIdx.x] = (i < n) ? cnt[i] : 0;
    __syncthreads();
    for (int s = 128; s; s >>= 1) {
        if (threadIdx.x < s) red[threadIdx.x] += red[threadIdx.x + s];
        __syncthreads();
    }
    if (threadIdx.x == 0) bsums[blockIdx.x] = red[0];
}

__global__ void scan_excl_single(int* __restrict__ data, int n) {
    __shared__ int buf[1024];
    __shared__ int carry_s;
    if (threadIdx.x == 0) carry_s = 0;
    __syncthreads();
    for (int base = 0; base < n; base += 1024) {
        int i = base + threadIdx.x;
        int v = (i < n) ? data[i] : 0;
        buf[threadIdx.x] = v;
        __syncthreads();
        for (int off = 1; off < 1024; off <<= 1) {
            int tv = (threadIdx.x >= off) ? buf[threadIdx.x - off] : 0;
            __syncthreads();
            buf[threadIdx.x] += tv;
            __syncthreads();
        }
        int incl = buf[threadIdx.x];
        int carry = carry_s;
        if (i < n) data[i] = carry + incl - v;
        __syncthreads();
        if (threadIdx.x == 1023) carry_s = carry + buf[1023];
        __syncthreads();
    }
}

__global__ void scan_rowptr(const int* __restrict__ cnt, const int* __restrict__ bsums,
                            int n, int* __restrict__ row_ptr) {
    __shared__ int buf[256];
    int i = blockIdx.x * 256 + threadIdx.x;
    int v = (i < n) ? cnt[i] : 0;
    buf[threadIdx.x] = v;
    __syncthreads();
    for (int off = 1; off < 256; off <<= 1) {
        int tv = (threadIdx.x >= off) ? buf[threadIdx.x - off] : 0;
        __syncthreads();
        buf[threadIdx.x] += tv;
        __syncthreads();
    }
    int excl = buf[threadIdx.x] - v + bsums[blockIdx.x];
    if (i < n) row_ptr[i] = excl;
    if (i == n - 1) row_ptr[n] = excl + v;
}

// ---------- fused layer v3: per-WAVE 16-row tiles, 2 LDS regions, barrier-free ----------
struct FusedArgs {
    int cntOff[4][3];
    int wtSlot[4][4];
    long dstBase[4];
    int nDst[4];
    int Rdt[4];
    int blsumOff[4];
    int btBase[5];   // in 16-row-tile units, heavy-first order
    int dtOf[4];
    int totalT16;
};

__device__ __forceinline__ void gather_pass(
    unsigned* __restrict__ L,          // this pass's 16x32-dword region
    const uint4* __restrict__ xq,
    const int* __restrict__ edge_src,
    const int* __restrict__ row_ptr,
    int cr, bool valid, int gr, int gp) {
    int rp0 = 0, rp1 = 0;
    if (valid) { rp0 = row_ptr[cr]; rp1 = row_ptr[cr + 1]; }
    float s[16];
    #pragma unroll
    for (int j = 0; j < 16; ++j) s[j] = 0.f;
    {   // static first-4-edges pipeline
        int idx4[4];
        #pragma unroll
        for (int j = 0; j < 4; ++j) {
            int ee = rp0 + j;
            idx4[j] = edge_src[(ee < rp1) ? ee : 0];
        }
        uint4 v0[4], v1[4];
        #pragma unroll
        for (int j = 0; j < 4; ++j) {
            bool ok = (rp0 + j < rp1);
            unsigned ofs = (unsigned)idx4[j] * 8u + (unsigned)gp * 2u;
            v0[j] = xq[ok ? ofs : 0u];
            v1[j] = xq[ok ? ofs + 1u : 0u];
        }
        #pragma unroll
        for (int j = 0; j < 4; ++j) {
            unsigned m = (rp0 + j < rp1) ? 0xFFFFFFFFu : 0u;
            acc8(s, v0[j], m);
            acc8(s + 8, v1[j], m);
        }
    }
    for (int e = rp0 + 4; e < rp1; e += 4) {   // leftover (deg>4 rows)
        int idx4[4];
        #pragma unroll
        for (int j = 0; j < 4; ++j) {
            int ee = e + j;
            idx4[j] = edge_src[(ee < rp1) ? ee : 0];
        }
        uint4 v0[4], v1[4];
        #pragma unroll
        for (int j = 0; j < 4; ++j) {
            bool ok = (e + j < rp1);
            unsigned ofs = (unsigned)idx4[j] * 8u + (unsigned)gp * 2u;
            v0[j] = xq[ok ? ofs : 0u];
            v1[j] = xq[ok ? ofs + 1u : 0u];
        }
        #pragma unroll
        for (int j = 0; j < 4; ++j) {
            unsigned m = (e + j < rp1) ? 0xFFFFFFFFu : 0u;
            acc8(s, v0[j], m);
            acc8(s + 8, v1[j], m);
        }
    }
    float inv = (rp1 > rp0) ? 1.0f / (float)(rp1 - rp0) : 0.f;
    unsigned base = (unsigned)gr * 32u;
    #pragma unroll
    for (int h = 0; h < 2; ++h) {
        int d = gp * 8 + h * 4;
        unsigned idxw = base + (unsigned)(d ^ ((gr & 7) << 2));
        uint4 o;
        o.x = packbf(s[h * 8 + 0] * inv, s[h * 8 + 1] * inv);
        o.y = packbf(s[h * 8 + 2] * inv, s[h * 8 + 3] * inv);
        o.z = packbf(s[h * 8 + 4] * inv, s[h * 8 + 5] * inv);
        o.w = packbf(s[h * 8 + 6] * inv, s[h * 8 + 7] * inv);
        *(uint4*)&L[idxw] = o;
    }
}

__device__ __forceinline__ void mfma_pass(f32x4* acc, const bf16_t* wb,
                                          bf16x8 a0, bf16x8 a1, int l16, int quad) {
    #pragma unroll
    for (int nt = 0; nt < 4; ++nt) {
        bf16x8 b0 = *(const bf16x8*)(wb + (nt * 16 + l16) * 64 + quad * 8);
        bf16x8 b1 = *(const bf16x8*)(wb + (nt * 16 + l16) * 64 + 32 + quad * 8);
        acc[nt] = __builtin_amdgcn_mfma_f32_16x16x32_bf16(a0, b0, acc[nt], 0, 0, 0);
        acc[nt] = __builtin_amdgcn_mfma_f32_16x16x32_bf16(a1, b1, acc[nt], 0, 0, 0);
    }
}

__global__ __launch_bounds__(256) void fused_layer(
    const __hip_bfloat16* __restrict__ xin,
    __hip_bfloat16* __restrict__ xout,
    const int* __restrict__ edge_src,
    const int* __restrict__ row_ptr,
    const bf16_t* __restrict__ wt,
    const float* __restrict__ blsum,
    FusedArgs fa) {
    __shared__ unsigned lds[4][2 * 512];   // per wave: 2 regions x 16 rows x 128B = 16KB/block

    int wv = threadIdx.x >> 6;
    int g = blockIdx.x * 4 + wv;
    if (g >= fa.totalT16) return;
    int slot = 0;
    while (slot < 3 && g >= fa.btBase[slot + 1]) ++slot;
    int dt = fa.dtOf[slot];
    int t0 = g - fa.btBase[slot];
    int nD = fa.nDst[dt];
    int R = fa.Rdt[dt];

    int lane = threadIdx.x & 63;
    int gr = lane >> 2, gp = lane & 3;     // gather: row 0..15, 32B part 0..3
    int row = t0 * 16 + gr;
    bool valid = (row < nD);
    int quad = lane >> 4, l16 = lane & 15; // MFMA roles

    const uint4* xq = (const uint4*)xin;
    unsigned* L = lds[wv];

    // self-pass A loads: issue early, consume at the end (in flight under gathers)
    const bf16_t* ab = (const bf16_t*)xin + (fa.dstBase[dt] + (long)t0 * 16) * 64;
    bf16x8 sa0 = *(const bf16x8*)(ab + l16 * 64 + quad * 8);
    bf16x8 sa1 = *(const bf16x8*)(ab + l16 * 64 + 32 + quad * 8);

    unsigned sw = (unsigned)((l16 & 7) << 2);
    unsigned o0 = (unsigned)l16 * 32u + ((unsigned)(quad * 4) ^ sw);
    unsigned o1 = (unsigned)l16 * 32u + ((unsigned)(16 + quad * 4) ^ sw);
    f32x4 acc[4] = {};

    // G0 -> region0, G1 -> region1
    gather_pass(L, xq, edge_src, row_ptr, fa.cntOff[dt][0] + row, valid, gr, gp);
    if (R > 1)
        gather_pass(L + 512, xq, edge_src, row_ptr, fa.cntOff[dt][1] + row, valid, gr, gp);

    asm volatile("s_waitcnt lgkmcnt(0)" ::: "memory");
    __builtin_amdgcn_sched_barrier(0);

    // read A-fragments p0/p1, then drain reads so region0 can be safely reused
    bf16x8 a00 = *(const bf16x8*)&L[o0];
    bf16x8 a01 = *(const bf16x8*)&L[o1];
    bf16x8 a10 = a00, a11 = a01;
    if (R > 1) { a10 = *(const bf16x8*)&L[512 + o0]; a11 = *(const bf16x8*)&L[512 + o1]; }
    asm volatile("s_waitcnt lgkmcnt(0)" ::: "memory");
    __builtin_amdgcn_sched_barrier(0);

    mfma_pass(acc, wt + (long)fa.wtSlot[dt][0] * 4096, a00, a01, l16, quad);
    if (R > 1)
        mfma_pass(acc, wt + (long)fa.wtSlot[dt][1] * 4096, a10, a11, l16, quad);

    if (R > 2) {
        // reuse region0 (p0 reads drained above)
        gather_pass(L, xq, edge_src, row_ptr, fa.cntOff[dt][2] + row, valid, gr, gp);
        asm volatile("s_waitcnt lgkmcnt(0)" ::: "memory");
        __builtin_amdgcn_sched_barrier(0);
        bf16x8 a20 = *(const bf16x8*)&L[o0];
        bf16x8 a21 = *(const bf16x8*)&L[o1];
        mfma_pass(acc, wt + (long)fa.wtSlot[dt][2] * 4096, a20, a21, l16, quad);
    }

    // self pass (x buffers padded +64 rows for tail overreads)
    mfma_pass(acc, wt + (long)fa.wtSlot[dt][3] * 4096, sa0, sa1, l16, quad);

    const float* bs = blsum + fa.blsumOff[dt];
    #pragma unroll
    for (int nt = 0; nt < 4; ++nt) {
        int col = nt * 16 + l16;
        float bv = bs[col];
        #pragma unroll
        for (int reg = 0; reg < 4; ++reg) {
            long dd = (long)t0 * 16 + quad * 4 + reg;
            if (dd < nD)
                xout[(fa.dstBase[dt] + dd) * 64 + col] =
                    __float2bfloat16(fmaxf(acc[nt][reg] + bv, 0.f));
        }
    }
}

// ---------- head: softplus(x@projW+projb) @ outW + outb ----------
__global__ __launch_bounds__(256) void head_k(
    const __hip_bfloat16* __restrict__ xc,
    const void* __restrict__ projW, const void* __restrict__ projb,
    const void* __restrict__ outW, const void* __restrict__ outb,
    void* __restrict__ out, const unsigned int* __restrict__ flags, int n) {
    __shared__ float PW[64 * 64];
    __shared__ float PB[64], OW[64];
    __shared__ float ROW[4][64];
    bool wf32 = flags[2] > 64;
    bool of32 = flags[1] > 64;
    int t = threadIdx.x;
    for (int i = t; i < 4096; i += 256) PW[i] = wload(projW, i, wf32);
    if (t < 64) { PB[t] = wload(projb, t, wf32); OW[t] = wload(outW, t, wf32); }
    int wid = t >> 6, lane = t & 63;
    int d = blockIdx.x * 4 + wid;
    ROW[wid][lane] = (d < n) ? __bfloat162float(xc[(long)d * H64 + lane]) : 0.f;
    __syncthreads();
    if (d < n) {
        float s = PB[lane];
        #pragma unroll 8
        for (int k = 0; k < 64; ++k) s += ROW[wid][k] * PW[k * 64 + lane];
        float sp = fmaxf(s, 0.f) + log1pf(expf(-fabsf(s)));
        float c = sp * OW[lane];
        #pragma unroll
        for (int off = 32; off; off >>= 1) c += __shfl_down(c, off, 64);
        if (lane == 0) {
            float rv = c + wload(outb, 0, wf32);
            if (of32) ((float*)out)[d] = rv;
            else ((__hip_bfloat16*)out)[d] = __float2bfloat16(rv);
        }
    }
}

extern "C" void kernel_launch(void* const* d_in, const int* in_sizes, int n_in,
                              void* d_out, int out_size, void* d_ws, size_t ws_size,
                              hipStream_t stream) {
    static const int rel_st[9] = {0, 0, 0, 1, 1, 2, 0, 1, 2};
    static const int rel_dt[9] = {0, 1, 2, 1, 2, 2, 3, 3, 3};
    static const int relsOf[4][3] = {{0, -1, -1}, {1, 3, -1}, {2, 4, 5}, {6, 7, 8}};
    static const int Rof[4] = {1, 2, 3, 3};
    static const int order[4] = {3, 0, 2, 1};   // heavy tiles first (cell, atom, motif, bond)

    long rows[4], rowoff[4], total = 0;
    for (int t = 0; t < 4; ++t) { rows[t] = in_sizes[t] / H64; rowoff[t] = total; total += rows[t]; }
    long NX = total * H64;
    long NXpad = (total + 64) * H64;           // +64 rows: tail-tile overread safety
    long Es[9], ET = 0;
    for (int r = 0; r < 9; ++r) { Es[r] = (long)in_sizes[11 + r] / 2; ET += Es[r]; }
    long cntoff[9], cntN = 0;
    for (int r = 0; r < 9; ++r) { cntoff[r] = cntN; cntN += rows[rel_dt[r]]; }
    long nb1 = (cntN + 255) / 256;

    unsigned int* flags = (unsigned int*)d_ws;
    char* wsbase = (char*)d_ws + 64;
    auto align16 = [](size_t v) { return (v + 15) & ~(size_t)15; };
    size_t off = 0;
    __hip_bfloat16* x0 = (__hip_bfloat16*)(wsbase + off);  off = align16(off + (size_t)NXpad * 2);
    __hip_bfloat16* x1 = (__hip_bfloat16*)(wsbase + off);  off = align16(off + (size_t)NXpad * 2);
    int* cnt_i = (int*)(wsbase + off);                     off = align16(off + (size_t)cntN * 4);
    int* row_ptr = (int*)(wsbase + off);                   off = align16(off + (size_t)(cntN + 1) * 4);
    int* rank = (int*)(wsbase + off);                      off = align16(off + (size_t)ET * 4);
    int* edge_src = (int*)(wsbase + off);                  off = align16(off + (size_t)ET * 4);
    int* bsums = (int*)(wsbase + off);                     off = align16(off + (size_t)nb1 * 4);
    bf16_t* wt = (bf16_t*)(wsbase + off);                  off = align16(off + (size_t)39 * 4096 * 2);
    float* blsum = (float*)(wsbase + off);                 off = align16(off + (size_t)12 * 64 * 4);

    // format detection
    hipMemsetAsync(d_ws, 0, 64, stream);
    int nwords = 16384;
    if (in_sizes[11] < nwords) nwords = in_sizes[11];
    detect_k<<<1, 256, 0, stream>>>((const unsigned int*)d_in[11], nwords,
                                    (const unsigned short*)d_in[0],
                                    (const unsigned short*)d_in[4], flags);

    // x inputs -> bf16 ws (single dispatch)
    ConvArgs ca;
    for (int t = 0; t < 4; ++t) { ca.src[t] = d_in[t]; ca.elemoff[t] = rowoff[t] * H64; }
    ca.elemoff[4] = NX;
    {
        int blocks = (int)((NX + 255) / 256); if (blocks > 8192) blocks = 8192;
        conv_in_all<<<blocks, 256, 0, stream>>>(ca, x0, flags);
    }

    // weight prep (transpose + pre-sum, bf16)
    prep_w<<<39, 256, 0, stream>>>(d_in[4], d_in[6], d_in[5], flags, wt, blsum);

    // CSR build (edge structure is layer-invariant)
    EdgeArgs ea;
    long ecum = 0;
    for (int r = 0; r < 9; ++r) {
        ea.ei[r] = (const int*)d_in[11 + r];
        ea.eoff[r] = ecum; ecum += Es[r];
        ea.cntoff[r] = (int)cntoff[r];
        ea.srcbase[r] = (int)rowoff[rel_st[r]];
    }
    ea.eoff[9] = ecum;

    hipMemsetAsync(cnt_i, 0, (size_t)cntN * 4, stream);
    count_all<<<(int)((ET + 255) / 256), 256, 0, stream>>>(ea, flags, cnt_i, rank);
    scan_bsum<<<(int)nb1, 256, 0, stream>>>(cnt_i, (int)cntN, bsums);
    scan_excl_single<<<1, 1024, 0, stream>>>(bsums, (int)nb1);
    scan_rowptr<<<(int)nb1, 256, 0, stream>>>(cnt_i, bsums, (int)cntN, row_ptr);
    fill_all<<<(int)((ET + 255) / 256), 256, 0, stream>>>(ea, flags, row_ptr, rank, edge_src);

    // fused-layer argument block (layer-invariant parts), 16-row tiles
    FusedArgs fa;
    int bb = 0;
    for (int s = 0; s < 4; ++s) {
        int dt = order[s];
        fa.dtOf[s] = dt;
        fa.btBase[s] = bb;
        bb += (int)((rows[dt] + 15) / 16);
    }
    fa.btBase[4] = bb;
    fa.totalT16 = bb;
    for (int dt = 0; dt < 4; ++dt) {
        fa.nDst[dt] = (int)rows[dt];
        fa.Rdt[dt] = Rof[dt];
        fa.dstBase[dt] = rowoff[dt];
        for (int p = 0; p < 3; ++p) {
            int rr = (p < Rof[dt]) ? relsOf[dt][p] : relsOf[dt][0];
            fa.cntOff[dt][p] = (int)cntoff[rr];
        }
    }

    // layers: fused gather+update, ping-pong x
    for (int l = 0; l < 3; ++l) {
        for (int dt = 0; dt < 4; ++dt) {
            fa.blsumOff[dt] = (l * 4 + dt) * 64;
            for (int p = 0; p < 3; ++p) {
                int rr = (p < Rof[dt]) ? relsOf[dt][p] : relsOf[dt][0];
                fa.wtSlot[dt][p] = l * 13 + rr;
            }
            fa.wtSlot[dt][3] = l * 13 + 9 + dt;
        }
        const __hip_bfloat16* xin = (l & 1) ? x1 : x0;
        __hip_bfloat16* xo = (l & 1) ? x0 : x1;
        fused_layer<<<(bb + 3) / 4, 256, 0, stream>>>(xin, xo, edge_src, row_ptr, wt, blsum, fa);
    }

    // 3 layers -> final state in x1
    head_k<<<(int)((rows[3] + 3) / 4), 256, 0, stream>>>(
        x1 + rowoff[3] * H64, d_in[7], d_in[8], d_in[9], d_in[10], d_out, flags, (int)rows[3]);
}

// Round 8
// 799.723 us; speedup vs baseline: 1.2721x; 1.0495x over previous
//
#include <hip/hip_runtime.h>
#include <hip/hip_bf16.h>

#define H64 64

typedef __bf16 bf16_t;
typedef __bf16 bf16x8 __attribute__((ext_vector_type(8)));
typedef float f32x4 __attribute__((ext_vector_type(4)));

// ---------- helpers ----------
__device__ __forceinline__ float wload(const void* p, long i, bool f32) {
    return f32 ? ((const float*)p)[i]
               : __bfloat162float(((const __hip_bfloat16*)p)[i]);
}
__device__ __forceinline__ float blo(unsigned v) { return __uint_as_float(v << 16); }
__device__ __forceinline__ float bhi(unsigned v) { return __uint_as_float(v & 0xffff0000u); }
__device__ __forceinline__ unsigned packbf(float lo, float hi) {
    __hip_bfloat162 t;
    t.x = __float2bfloat16(lo);
    t.y = __float2bfloat16(hi);
    return *(unsigned*)&t;
}
__device__ __forceinline__ void acc8(float* s, uint4 v, unsigned m) {
    s[0] += blo(v.x & m); s[1] += bhi(v.x & m);
    s[2] += blo(v.y & m); s[3] += bhi(v.y & m);
    s[4] += blo(v.z & m); s[5] += bhi(v.z & m);
    s[6] += blo(v.w & m); s[7] += bhi(v.w & m);
}

// ---------- runtime format detection ----------
// flags[0] != 0 -> edge indices int32 (odd words nonzero); ==0 -> int64
// flags[1] > 64 -> x tensors f32; else bf16.  flags[2] > 64 -> weights f32.
__global__ void detect_k(const unsigned int* __restrict__ eiw, int nwords,
                         const unsigned short* __restrict__ xw,
                         const unsigned short* __restrict__ ww,
                         unsigned int* __restrict__ flags) {
    int t = threadIdx.x;
    unsigned int acc = 0;
    for (int i = 1 + 2 * t; i < nwords; i += 512) acc |= eiw[i];
    if (acc) atomicOr(&flags[0], acc);
    unsigned int cx = 0, cw = 0;
    for (int i = t; i < 8192; i += 256) {
        unsigned short w = xw[i];
        unsigned int e = (w >> 7) & 0xFF;
        if ((w & 0x7FFF) && (e == 0xFF || e < 0x40)) cx++;
        w = ww[i];
        e = (w >> 7) & 0xFF;
        if ((w & 0x7FFF) && (e == 0xFF || e < 0x40)) cw++;
    }
    if (cx) atomicAdd(&flags[1], cx);
    if (cw) atomicAdd(&flags[2], cw);
}

// ---------- convert all x inputs -> bf16 ws storage (uint4-vectorized) ----------
// one uint4 (8 bf16) per thread; block-uniform type resolution via block ranges.
struct ConvArgs {
    const void* src[4];
    long ubase[4];    // dst offset per type, in uint4 units
    long units[4];    // uint4 units per type
    int blkBase[5];   // cumulative block ranges per type
};
__global__ void conv_in_all(ConvArgs ca, __hip_bfloat16* __restrict__ dst,
                            const unsigned int* __restrict__ flags) {
    bool xf32 = flags[1] > 64;
    int b = blockIdx.x;
    int t = 0;
    while (t < 3 && b >= ca.blkBase[t + 1]) ++t;
    long lu = (long)(b - ca.blkBase[t]) * 256 + threadIdx.x;
    if (lu >= ca.units[t]) return;
    uint4* d4 = (uint4*)dst + ca.ubase[t] + lu;
    if (xf32) {
        const uint4* s = (const uint4*)ca.src[t] + 2 * lu;
        uint4 a = s[0], c = s[1];
        uint4 o;
        o.x = packbf(__uint_as_float(a.x), __uint_as_float(a.y));
        o.y = packbf(__uint_as_float(a.z), __uint_as_float(a.w));
        o.z = packbf(__uint_as_float(c.x), __uint_as_float(c.y));
        o.w = packbf(__uint_as_float(c.z), __uint_as_float(c.w));
        *d4 = o;
    } else {
        *d4 = ((const uint4*)ca.src[t])[lu];
    }
}

// ---------- weight prep: bf16, transposed WT[n][k]; Wr pre-summed per (l,dt) ----------
// blockIdx.x = l*13 + p.  p<9: WT of Wl[l,p].  p in 9..12: dt=p-9, WT of sum(Wr) + blsum.
__global__ void prep_w(const void* __restrict__ Wl, const void* __restrict__ Wr,
                       const void* __restrict__ bl, const unsigned int* __restrict__ flags,
                       bf16_t* __restrict__ wt, float* __restrict__ blsum) {
    const int rel_dt[9] = {0, 1, 2, 1, 2, 2, 3, 3, 3};
    bool wf32 = flags[2] > 64;
    int l = blockIdx.x / 13, p = blockIdx.x % 13;
    bf16_t* dst = wt + (long)blockIdx.x * 4096;
    for (int i = threadIdx.x; i < 4096; i += 256) {
        int n = i >> 6, k = i & 63;
        float v;
        if (p < 9) {
            v = wload(Wl, (long)(l * 9 + p) * 4096 + k * 64 + n, wf32);
        } else {
            int dt = p - 9;
            v = 0.f;
            for (int r = 0; r < 9; ++r)
                if (rel_dt[r] == dt) v += wload(Wr, (long)(l * 9 + r) * 4096 + k * 64 + n, wf32);
        }
        __hip_bfloat16 h = __float2bfloat16(v);
        dst[i] = *(bf16_t*)&h;
    }
    if (p >= 9 && threadIdx.x < 64) {
        int dt = p - 9;
        float s = 0.f;
        for (int r = 0; r < 9; ++r)
            if (rel_dt[r] == dt) s += wload(bl, (long)(l * 9 + r) * 64 + threadIdx.x, wf32);
        blsum[(l * 4 + dt) * 64 + threadIdx.x] = s;
    }
}

// ---------- consolidated CSR build (2 edges per thread) ----------
struct EdgeArgs {
    const int* ei[9];
    long eoff[10];    // edge offsets, cumulative
    long e2off[10];   // 2-edge-unit offsets, cumulative
    int cntoff[9];
    int srcbase[9];
};

// count + emit per-edge rank
__global__ void count_all(EdgeArgs ea, const unsigned int* __restrict__ flags,
                          int* __restrict__ cnt, int* __restrict__ rank) {
    long u = (long)blockIdx.x * 256 + threadIdx.x;
    if (u >= ea.e2off[9]) return;
    int r = 0;
    while (r < 8 && u >= ea.e2off[r + 1]) ++r;
    long el2 = u - ea.e2off[r];
    long E = ea.eoff[r + 1] - ea.eoff[r];
    long e0 = 2 * el2;
    bool two = (e0 + 1 < E);
    bool is64 = (flags[0] == 0u);
    const int* ei = ea.ei[r];
    int d0, d1 = 0;
    if (is64) { d0 = ei[2 * E + 2 * e0]; if (two) d1 = ei[2 * E + 2 * e0 + 2]; }
    else      { d0 = ei[E + e0];         if (two) d1 = ei[E + e0 + 1]; }
    int base = ea.cntoff[r];
    long eg = ea.eoff[r] + e0;
    rank[eg] = atomicAdd(&cnt[base + d0], 1);
    if (two) rank[eg + 1] = atomicAdd(&cnt[base + d1], 1);
}

// atomic-free fill: pos = row_ptr[dst] + rank[e]
__global__ void fill_all(EdgeArgs ea, const unsigned int* __restrict__ flags,
                         const int* __restrict__ row_ptr, const int* __restrict__ rank,
                         int* __restrict__ edge_src) {
    long u = (long)blockIdx.x * 256 + threadIdx.x;
    if (u >= ea.e2off[9]) return;
    int r = 0;
    while (r < 8 && u >= ea.e2off[r + 1]) ++r;
    long el2 = u - ea.e2off[r];
    long E = ea.eoff[r + 1] - ea.eoff[r];
    long e0 = 2 * el2;
    bool two = (e0 + 1 < E);
    bool is64 = (flags[0] == 0u);
    const int* ei = ea.ei[r];
    int s0, d0, s1 = 0, d1 = 0;
    if (is64) {
        s0 = ei[2 * e0];     d0 = ei[2 * E + 2 * e0];
        if (two) { s1 = ei[2 * e0 + 2]; d1 = ei[2 * E + 2 * e0 + 2]; }
    } else {
        s0 = ei[e0];         d0 = ei[E + e0];
        if (two) { s1 = ei[e0 + 1]; d1 = ei[E + e0 + 1]; }
    }
    int base = ea.cntoff[r], sb = ea.srcbase[r];
    long eg = ea.eoff[r] + e0;
    edge_src[row_ptr[base + d0] + rank[eg]] = sb + s0;
    if (two) edge_src[row_ptr[base + d1] + rank[eg + 1]] = sb + s1;
}

__global__ void scan_bsum(const int* __restrict__ cnt, int n, int* __restrict__ bsums) {
    __shared__ int red[256];
    int i = blockIdx.x * 256 + threadIdx.x;
    red[threadIdx.x] = (i < n) ? cnt[i] : 0;
    __syncthreads();
    for (int s = 128; s; s >>= 1) {
        if (threadIdx.x < s) red[threadIdx.x] += red[threadIdx.x + s];
        __syncthreads();
    }
    if (threadIdx.x == 0) bsums[blockIdx.x] = red[0];
}

__global__ void scan_excl_single(int* __restrict__ data, int n) {
    __shared__ int buf[1024];
    __shared__ int carry_s;
    if (threadIdx.x == 0) carry_s = 0;
    __syncthreads();
    for (int base = 0; base < n; base += 1024) {
        int i = base + threadIdx.x;
        int v = (i < n) ? data[i] : 0;
        buf[threadIdx.x] = v;
        __syncthreads();
        for (int off = 1; off < 1024; off <<= 1) {
            int tv = (threadIdx.x >= off) ? buf[threadIdx.x - off] : 0;
            __syncthreads();
            buf[threadIdx.x] += tv;
            __syncthreads();
        }
        int incl = buf[threadIdx.x];
        int carry = carry_s;
        if (i < n) data[i] = carry + incl - v;
        __syncthreads();
        if (threadIdx.x == 1023) carry_s = carry + buf[1023];
        __syncthreads();
    }
}

__global__ void scan_rowptr(const int* __restrict__ cnt, const int* __restrict__ bsums,
                            int n, int* __restrict__ row_ptr) {
    __shared__ int buf[256];
    int i = blockIdx.x * 256 + threadIdx.x;
    int v = (i < n) ? cnt[i] : 0;
    buf[threadIdx.x] = v;
    __syncthreads();
    for (int off = 1; off < 256; off <<= 1) {
        int tv = (threadIdx.x >= off) ? buf[threadIdx.x - off] : 0;
        __syncthreads();
        buf[threadIdx.x] += tv;
        __syncthreads();
    }
    int excl = buf[threadIdx.x] - v + bsums[blockIdx.x];
    if (i < n) row_ptr[i] = excl;
    if (i == n - 1) row_ptr[n] = excl + v;
}

// ---------- fused layer v3: per-WAVE 16-row tiles, 2 LDS regions, barrier-free ----------
struct FusedArgs {
    int cntOff[4][3];
    int wtSlot[4][4];
    long dstBase[4];
    int nDst[4];
    int Rdt[4];
    int blsumOff[4];
    int btBase[5];   // in 16-row-tile units, heavy-first order
    int dtOf[4];
    int totalT16;
};

__device__ __forceinline__ void gather_pass(
    unsigned* __restrict__ L,          // this pass's 16x32-dword region
    const uint4* __restrict__ xq,
    const int* __restrict__ edge_src,
    const int* __restrict__ row_ptr,
    int cr, bool valid, int gr, int gp) {
    int rp0 = 0, rp1 = 0;
    if (valid) { rp0 = row_ptr[cr]; rp1 = row_ptr[cr + 1]; }
    float s[16];
    #pragma unroll
    for (int j = 0; j < 16; ++j) s[j] = 0.f;
    {   // static first-4-edges pipeline
        int idx4[4];
        #pragma unroll
        for (int j = 0; j < 4; ++j) {
            int ee = rp0 + j;
            idx4[j] = edge_src[(ee < rp1) ? ee : 0];
        }
        uint4 v0[4], v1[4];
        #pragma unroll
        for (int j = 0; j < 4; ++j) {
            bool ok = (rp0 + j < rp1);
            unsigned ofs = (unsigned)idx4[j] * 8u + (unsigned)gp * 2u;
            v0[j] = xq[ok ? ofs : 0u];
            v1[j] = xq[ok ? ofs + 1u : 0u];
        }
        #pragma unroll
        for (int j = 0; j < 4; ++j) {
            unsigned m = (rp0 + j < rp1) ? 0xFFFFFFFFu : 0u;
            acc8(s, v0[j], m);
            acc8(s + 8, v1[j], m);
        }
    }
    for (int e = rp0 + 4; e < rp1; e += 4) {   // leftover (deg>4 rows)
        int idx4[4];
        #pragma unroll
        for (int j = 0; j < 4; ++j) {
            int ee = e + j;
            idx4[j] = edge_src[(ee < rp1) ? ee : 0];
        }
        uint4 v0[4], v1[4];
        #pragma unroll
        for (int j = 0; j < 4; ++j) {
            bool ok = (e + j < rp1);
            unsigned ofs = (unsigned)idx4[j] * 8u + (unsigned)gp * 2u;
            v0[j] = xq[ok ? ofs : 0u];
            v1[j] = xq[ok ? ofs + 1u : 0u];
        }
        #pragma unroll
        for (int j = 0; j < 4; ++j) {
            unsigned m = (e + j < rp1) ? 0xFFFFFFFFu : 0u;
            acc8(s, v0[j], m);
            acc8(s + 8, v1[j], m);
        }
    }
    float inv = (rp1 > rp0) ? 1.0f / (float)(rp1 - rp0) : 0.f;
    unsigned base = (unsigned)gr * 32u;
    #pragma unroll
    for (int h = 0; h < 2; ++h) {
        int d = gp * 8 + h * 4;
        unsigned idxw = base + (unsigned)(d ^ ((gr & 7) << 2));
        uint4 o;
        o.x = packbf(s[h * 8 + 0] * inv, s[h * 8 + 1] * inv);
        o.y = packbf(s[h * 8 + 2] * inv, s[h * 8 + 3] * inv);
        o.z = packbf(s[h * 8 + 4] * inv, s[h * 8 + 5] * inv);
        o.w = packbf(s[h * 8 + 6] * inv, s[h * 8 + 7] * inv);
        *(uint4*)&L[idxw] = o;
    }
}

__device__ __forceinline__ void mfma_pass(f32x4* acc, const bf16_t* wb,
                                          bf16x8 a0, bf16x8 a1, int l16, int quad) {
    #pragma unroll
    for (int nt = 0; nt < 4; ++nt) {
        bf16x8 b0 = *(const bf16x8*)(wb + (nt * 16 + l16) * 64 + quad * 8);
        bf16x8 b1 = *(const bf16x8*)(wb + (nt * 16 + l16) * 64 + 32 + quad * 8);
        acc[nt] = __builtin_amdgcn_mfma_f32_16x16x32_bf16(a0, b0, acc[nt], 0, 0, 0);
        acc[nt] = __builtin_amdgcn_mfma_f32_16x16x32_bf16(a1, b1, acc[nt], 0, 0, 0);
    }
}

__global__ __launch_bounds__(256) void fused_layer(
    const __hip_bfloat16* __restrict__ xin,
    __hip_bfloat16* __restrict__ xout,
    const int* __restrict__ edge_src,
    const int* __restrict__ row_ptr,
    const bf16_t* __restrict__ wt,
    const float* __restrict__ blsum,
    FusedArgs fa) {
    __shared__ unsigned lds[4][2 * 512];   // per wave: 2 regions x 16 rows x 128B = 16KB/block

    int wv = threadIdx.x >> 6;
    int g = blockIdx.x * 4 + wv;
    if (g >= fa.totalT16) return;
    int slot = 0;
    while (slot < 3 && g >= fa.btBase[slot + 1]) ++slot;
    int dt = fa.dtOf[slot];
    int t0 = g - fa.btBase[slot];
    int nD = fa.nDst[dt];
    int R = fa.Rdt[dt];

    int lane = threadIdx.x & 63;
    int gr = lane >> 2, gp = lane & 3;     // gather: row 0..15, 32B part 0..3
    int row = t0 * 16 + gr;
    bool valid = (row < nD);
    int quad = lane >> 4, l16 = lane & 15; // MFMA roles

    const uint4* xq = (const uint4*)xin;
    unsigned* L = lds[wv];

    // self-pass A loads: issue early, consume at the end (in flight under gathers)
    const bf16_t* ab = (const bf16_t*)xin + (fa.dstBase[dt] + (long)t0 * 16) * 64;
    bf16x8 sa0 = *(const bf16x8*)(ab + l16 * 64 + quad * 8);
    bf16x8 sa1 = *(const bf16x8*)(ab + l16 * 64 + 32 + quad * 8);

    unsigned sw = (unsigned)((l16 & 7) << 2);
    unsigned o0 = (unsigned)l16 * 32u + ((unsigned)(quad * 4) ^ sw);
    unsigned o1 = (unsigned)l16 * 32u + ((unsigned)(16 + quad * 4) ^ sw);
    f32x4 acc[4] = {};

    // G0 -> region0, G1 -> region1
    gather_pass(L, xq, edge_src, row_ptr, fa.cntOff[dt][0] + row, valid, gr, gp);
    if (R > 1)
        gather_pass(L + 512, xq, edge_src, row_ptr, fa.cntOff[dt][1] + row, valid, gr, gp);

    asm volatile("s_waitcnt lgkmcnt(0)" ::: "memory");
    __builtin_amdgcn_sched_barrier(0);

    // read A-fragments p0/p1, then drain reads so region0 can be safely reused
    bf16x8 a00 = *(const bf16x8*)&L[o0];
    bf16x8 a01 = *(const bf16x8*)&L[o1];
    bf16x8 a10 = a00, a11 = a01;
    if (R > 1) { a10 = *(const bf16x8*)&L[512 + o0]; a11 = *(const bf16x8*)&L[512 + o1]; }
    asm volatile("s_waitcnt lgkmcnt(0)" ::: "memory");
    __builtin_amdgcn_sched_barrier(0);

    mfma_pass(acc, wt + (long)fa.wtSlot[dt][0] * 4096, a00, a01, l16, quad);
    if (R > 1)
        mfma_pass(acc, wt + (long)fa.wtSlot[dt][1] * 4096, a10, a11, l16, quad);

    if (R > 2) {
        // reuse region0 (p0 reads drained above)
        gather_pass(L, xq, edge_src, row_ptr, fa.cntOff[dt][2] + row, valid, gr, gp);
        asm volatile("s_waitcnt lgkmcnt(0)" ::: "memory");
        __builtin_amdgcn_sched_barrier(0);
        bf16x8 a20 = *(const bf16x8*)&L[o0];
        bf16x8 a21 = *(const bf16x8*)&L[o1];
        mfma_pass(acc, wt + (long)fa.wtSlot[dt][2] * 4096, a20, a21, l16, quad);
    }

    // self pass (x buffers padded +64 rows for tail overreads)
    mfma_pass(acc, wt + (long)fa.wtSlot[dt][3] * 4096, sa0, sa1, l16, quad);

    const float* bs = blsum + fa.blsumOff[dt];
    #pragma unroll
    for (int nt = 0; nt < 4; ++nt) {
        int col = nt * 16 + l16;
        float bv = bs[col];
        #pragma unroll
        for (int reg = 0; reg < 4; ++reg) {
            long dd = (long)t0 * 16 + quad * 4 + reg;
            if (dd < nD)
                xout[(fa.dstBase[dt] + dd) * 64 + col] =
                    __float2bfloat16(fmaxf(acc[nt][reg] + bv, 0.f));
        }
    }
}

// ---------- head: softplus(x@projW+projb) @ outW + outb ----------
__global__ __launch_bounds__(256) void head_k(
    const __hip_bfloat16* __restrict__ xc,
    const void* __restrict__ projW, const void* __restrict__ projb,
    const void* __restrict__ outW, const void* __restrict__ outb,
    void* __restrict__ out, const unsigned int* __restrict__ flags, int n) {
    __shared__ float PW[64 * 64];
    __shared__ float PB[64], OW[64];
    __shared__ float ROW[4][64];
    bool wf32 = flags[2] > 64;
    bool of32 = flags[1] > 64;
    int t = threadIdx.x;
    for (int i = t; i < 4096; i += 256) PW[i] = wload(projW, i, wf32);
    if (t < 64) { PB[t] = wload(projb, t, wf32); OW[t] = wload(outW, t, wf32); }
    int wid = t >> 6, lane = t & 63;
    int d = blockIdx.x * 4 + wid;
    ROW[wid][lane] = (d < n) ? __bfloat162float(xc[(long)d * H64 + lane]) : 0.f;
    __syncthreads();
    if (d < n) {
        float s = PB[lane];
        #pragma unroll 8
        for (int k = 0; k < 64; ++k) s += ROW[wid][k] * PW[k * 64 + lane];
        float sp = fmaxf(s, 0.f) + log1pf(expf(-fabsf(s)));
        float c = sp * OW[lane];
        #pragma unroll
        for (int off = 32; off; off >>= 1) c += __shfl_down(c, off, 64);
        if (lane == 0) {
            float rv = c + wload(outb, 0, wf32);
            if (of32) ((float*)out)[d] = rv;
            else ((__hip_bfloat16*)out)[d] = __float2bfloat16(rv);
        }
    }
}

extern "C" void kernel_launch(void* const* d_in, const int* in_sizes, int n_in,
                              void* d_out, int out_size, void* d_ws, size_t ws_size,
                              hipStream_t stream) {
    static const int rel_st[9] = {0, 0, 0, 1, 1, 2, 0, 1, 2};
    static const int rel_dt[9] = {0, 1, 2, 1, 2, 2, 3, 3, 3};
    static const int relsOf[4][3] = {{0, -1, -1}, {1, 3, -1}, {2, 4, 5}, {6, 7, 8}};
    static const int Rof[4] = {1, 2, 3, 3};
    static const int order[4] = {3, 0, 2, 1};   // heavy tiles first (cell, atom, motif, bond)

    long rows[4], rowoff[4], total = 0;
    for (int t = 0; t < 4; ++t) { rows[t] = in_sizes[t] / H64; rowoff[t] = total; total += rows[t]; }
    long NX = total * H64;
    long NXpad = (total + 64) * H64;           // +64 rows: tail-tile overread safety
    long Es[9], ET = 0;
    for (int r = 0; r < 9; ++r) { Es[r] = (long)in_sizes[11 + r] / 2; ET += Es[r]; }
    long cntoff[9], cntN = 0;
    for (int r = 0; r < 9; ++r) { cntoff[r] = cntN; cntN += rows[rel_dt[r]]; }
    long nb1 = (cntN + 255) / 256;

    unsigned int* flags = (unsigned int*)d_ws;
    char* wsbase = (char*)d_ws + 64;
    auto align16 = [](size_t v) { return (v + 15) & ~(size_t)15; };
    size_t off = 0;
    __hip_bfloat16* x0 = (__hip_bfloat16*)(wsbase + off);  off = align16(off + (size_t)NXpad * 2);
    __hip_bfloat16* x1 = (__hip_bfloat16*)(wsbase + off);  off = align16(off + (size_t)NXpad * 2);
    int* cnt_i = (int*)(wsbase + off);                     off = align16(off + (size_t)cntN * 4);
    int* row_ptr = (int*)(wsbase + off);                   off = align16(off + (size_t)(cntN + 1) * 4);
    int* rank = (int*)(wsbase + off);                      off = align16(off + (size_t)ET * 4);
    int* edge_src = (int*)(wsbase + off);                  off = align16(off + (size_t)ET * 4);
    int* bsums = (int*)(wsbase + off);                     off = align16(off + (size_t)nb1 * 4);
    bf16_t* wt = (bf16_t*)(wsbase + off);                  off = align16(off + (size_t)39 * 4096 * 2);
    float* blsum = (float*)(wsbase + off);                 off = align16(off + (size_t)12 * 64 * 4);

    // format detection
    hipMemsetAsync(d_ws, 0, 64, stream);
    int nwords = 16384;
    if (in_sizes[11] < nwords) nwords = in_sizes[11];
    detect_k<<<1, 256, 0, stream>>>((const unsigned int*)d_in[11], nwords,
                                    (const unsigned short*)d_in[0],
                                    (const unsigned short*)d_in[4], flags);

    // x inputs -> bf16 ws (uint4-vectorized, block-ranged by type)
    ConvArgs ca;
    int cb = 0;
    for (int t = 0; t < 4; ++t) {
        ca.src[t] = d_in[t];
        ca.ubase[t] = rowoff[t] * 8;          // 64 elem/row = 8 uint4
        ca.units[t] = rows[t] * 8;
        ca.blkBase[t] = cb;
        cb += (int)((ca.units[t] + 255) / 256);
    }
    ca.blkBase[4] = cb;
    conv_in_all<<<cb, 256, 0, stream>>>(ca, x0, flags);

    // weight prep (transpose + pre-sum, bf16)
    prep_w<<<39, 256, 0, stream>>>(d_in[4], d_in[6], d_in[5], flags, wt, blsum);

    // CSR build (edge structure is layer-invariant), 2 edges per thread
    EdgeArgs ea;
    long ecum = 0, e2cum = 0;
    for (int r = 0; r < 9; ++r) {
        ea.ei[r] = (const int*)d_in[11 + r];
        ea.eoff[r] = ecum;   ecum += Es[r];
        ea.e2off[r] = e2cum; e2cum += (Es[r] + 1) / 2;
        ea.cntoff[r] = (int)cntoff[r];
        ea.srcbase[r] = (int)rowoff[rel_st[r]];
    }
    ea.eoff[9] = ecum;
    ea.e2off[9] = e2cum;

    hipMemsetAsync(cnt_i, 0, (size_t)cntN * 4, stream);
    count_all<<<(int)((e2cum + 255) / 256), 256, 0, stream>>>(ea, flags, cnt_i, rank);
    scan_bsum<<<(int)nb1, 256, 0, stream>>>(cnt_i, (int)cntN, bsums);
    scan_excl_single<<<1, 1024, 0, stream>>>(bsums, (int)nb1);
    scan_rowptr<<<(int)nb1, 256, 0, stream>>>(cnt_i, bsums, (int)cntN, row_ptr);
    fill_all<<<(int)((e2cum + 255) / 256), 256, 0, stream>>>(ea, flags, row_ptr, rank, edge_src);

    // fused-layer argument block (layer-invariant parts), 16-row tiles
    FusedArgs fa;
    int bb = 0;
    for (int s = 0; s < 4; ++s) {
        int dt = order[s];
        fa.dtOf[s] = dt;
        fa.btBase[s] = bb;
        bb += (int)((rows[dt] + 15) / 16);
    }
    fa.btBase[4] = bb;
    fa.totalT16 = bb;
    for (int dt = 0; dt < 4; ++dt) {
        fa.nDst[dt] = (int)rows[dt];
        fa.Rdt[dt] = Rof[dt];
        fa.dstBase[dt] = rowoff[dt];
        for (int p = 0; p < 3; ++p) {
            int rr = (p < Rof[dt]) ? relsOf[dt][p] : relsOf[dt][0];
            fa.cntOff[dt][p] = (int)cntoff[rr];
        }
    }

    // layers: fused gather+update, ping-pong x
    for (int l = 0; l < 3; ++l) {
        for (int dt = 0; dt < 4; ++dt) {
            fa.blsumOff[dt] = (l * 4 + dt) * 64;
            for (int p = 0; p < 3; ++p) {
                int rr = (p < Rof[dt]) ? relsOf[dt][p] : relsOf[dt][0];
                fa.wtSlot[dt][p] = l * 13 + rr;
            }
            fa.wtSlot[dt][3] = l * 13 + 9 + dt;
        }
        const __hip_bfloat16* xin = (l & 1) ? x1 : x0;
        __hip_bfloat16* xo = (l & 1) ? x0 : x1;
        fused_layer<<<(bb + 3) / 4, 256, 0, stream>>>(xin, xo, edge_src, row_ptr, wt, blsum, fa);
    }

    // 3 layers -> final state in x1
    head_k<<<(int)((rows[3] + 3) / 4), 256, 0, stream>>>(
        x1 + rowoff[3] * H64, d_in[7], d_in[8], d_in[9], d_in[10], d_out, flags, (int)rows[3]);
}